// Round 2
// baseline (194.767 us; speedup 1.0000x reference)
//
#include <hip/hip_runtime.h>

// HGNN forward, MI355X. fp32 throughout.
// Algebra: masked-mean (sums ALL neighbors, scales by 1/cnt_nonzero) commutes
// with the linear maps, so we average embeddings first, then do one pair of
// 64x64 matmuls per row. Wave-per-row, lane j = output element j, W rows in
// VGPRs, x broadcast via v_readlane.
// R2: 1 row per wave everywhere (k_usu/k_dsd1: 8192 waves, k_dsd2/k_fin: 1024)
// to fix the 18% occupancy / 29% VALUBusy latency-bound profile of R1.

__device__ __forceinline__ int rfl(int v) { return __builtin_amdgcn_readfirstlane(v); }

__device__ __forceinline__ float bcastf(float v, int l) {
    return __int_as_float(__builtin_amdgcn_readlane(__float_as_int(v), l));
}

__device__ __forceinline__ float leakyf(float x) {
    return x >= 0.f ? x : 0.2f * x;
}

__device__ __forceinline__ void load_wrow(float (&w)[64], const float* __restrict__ W, int lane) {
    const float4* p = reinterpret_cast<const float4*>(W) + lane * 16;
#pragma unroll
    for (int t = 0; t < 16; ++t) {
        float4 v = p[t];
        w[4*t+0] = v.x; w[4*t+1] = v.y; w[4*t+2] = v.z; w[4*t+3] = v.w;
    }
}

// out_j = sum_k x[k] * w[j][k]   (x element k lives in lane k's reg)
__device__ __forceinline__ float dot1(float x, const float (&w)[64]) {
    float a0=0.f, a1=0.f, a2=0.f, a3=0.f;
#pragma unroll
    for (int k = 0; k < 64; k += 4) {
        a0 = fmaf(bcastf(x, k+0), w[k+0], a0);
        a1 = fmaf(bcastf(x, k+1), w[k+1], a1);
        a2 = fmaf(bcastf(x, k+2), w[k+2], a2);
        a3 = fmaf(bcastf(x, k+3), w[k+3], a3);
    }
    return (a0 + a1) + (a2 + a3);
}

// out_j = sum_k xs[k]*w1[j][k] + xm[k]*w2[j][k]
__device__ __forceinline__ float dot2(float xs, float xm,
                                      const float (&w1)[64], const float (&w2)[64]) {
    float a0=0.f, a1=0.f, a2=0.f, a3=0.f;
#pragma unroll
    for (int k = 0; k < 64; k += 2) {
        float s0 = bcastf(xs, k+0), m0 = bcastf(xm, k+0);
        float s1 = bcastf(xs, k+1), m1 = bcastf(xm, k+1);
        a0 = fmaf(s0, w1[k+0], a0);
        a1 = fmaf(m0, w2[k+0], a1);
        a2 = fmaf(s1, w1[k+1], a2);
        a3 = fmaf(m1, w2[k+1], a3);
    }
    return (a0 + a1) + (a2 + a3);
}

// ---- dsd stage 1: emb_s1[b,h1,:] = leaky((A+es)@W21^T + (A*es)@W22^T) ----
// rows = B*H1 = 8192; one wave per row
__global__ __launch_bounds__(256) void k_dsd1(
    const float* __restrict__ E_s, const float* __restrict__ E_d,
    const float* __restrict__ W21, const float* __restrict__ W22,
    const int* __restrict__ dsd_1, const int* __restrict__ dsd_2,
    float* __restrict__ emb_s1)
{
    const int lane = threadIdx.x & 63;
    const int row  = rfl((int)((blockIdx.x * blockDim.x + threadIdx.x) >> 6)); // 0..8191
    int is  = dsd_1[row];
    float es = E_s[(size_t)is * 64 + lane];
    const int* d2 = dsd_2 + (size_t)row * 8;
    float sA0 = 0.f, sA1 = 0.f; int cnt = 0;
#pragma unroll
    for (int h2 = 0; h2 < 8; h2 += 2) {
        int id0 = d2[h2], id1 = d2[h2 + 1];
        cnt += (id0 != 0) + (id1 != 0);
        sA0 += E_d[(size_t)id0 * 64 + lane];      // E_d[0] == 0, safe to always add
        sA1 += E_d[(size_t)id1 * 64 + lane];
    }
    float sA = sA0 + sA1;
    float wgt = cnt > 0 ? 1.f / ((float)cnt + 1e-8f) : 0.f;
    float A = sA * wgt;
    float w1[64], w2[64];
    load_wrow(w1, W21, lane);
    load_wrow(w2, W22, lane);
    emb_s1[(size_t)row * 64 + lane] = leakyf(dot2(A + es, A * es, w1, w2));
}

// ---- dsd stage 2: emb_dise[b,:] = leaky((A3+td)@W11^T + (A3*td)@W12^T) ----
// rows = B = 1024; one wave per row
__global__ __launch_bounds__(256) void k_dsd2(
    const float* __restrict__ E_d,
    const float* __restrict__ W11, const float* __restrict__ W12,
    const int* __restrict__ label, const int* __restrict__ dsd_1,
    const float* __restrict__ emb_s1, float* __restrict__ emb_dise)
{
    const int lane = threadIdx.x & 63;
    const int b    = rfl((int)((blockIdx.x * blockDim.x + threadIdx.x) >> 6)); // 0..1023
    float sE0 = 0.f, sE1 = 0.f; int cnt = 0;
#pragma unroll
    for (int h1 = 0; h1 < 8; h1 += 2) {
        sE0 += emb_s1[(size_t)(b * 8 + h1) * 64 + lane];
        sE1 += emb_s1[(size_t)(b * 8 + h1 + 1) * 64 + lane];
        cnt += (dsd_1[b * 8 + h1] != 0) + (dsd_1[b * 8 + h1 + 1] != 0);
    }
    float wgt = cnt > 0 ? 1.f / ((float)cnt + 1e-8f) : 0.f;
    float A3 = (sE0 + sE1) * wgt;
    float td = E_d[(size_t)label[b] * 64 + lane];
    float w1[64], w2[64];
    load_wrow(w1, W11, lane);
    load_wrow(w2, W12, lane);
    emb_dise[(size_t)b * 64 + lane] = leakyf(dot2(A3 + td, A3 * td, w1, w2));
}

// ---- usu stages 1+2 fused per (b,u1): es1[p,:] ----
// p = B*U1 = 8192; one wave per p. Per p: 8 u2-rows (avg 16 E_s rows, W3
// matmul, leaky, accumulate), then pair matmul W21u/W22u.
__global__ __launch_bounds__(256) void k_usu(
    const float* __restrict__ E_s,
    const float* __restrict__ W3, const float* __restrict__ W21u, const float* __restrict__ W22u,
    const int* __restrict__ usu_1, const int* __restrict__ usu_2, const int* __restrict__ usu_3,
    float* __restrict__ es1)
{
    const int lane = threadIdx.x & 63;
    const int p    = rfl((int)((blockIdx.x * blockDim.x + threadIdx.x) >> 6)); // 0..8191
    float w3[64];
    load_wrow(w3, W3, lane);
    float sE = 0.f;
    for (int u2 = 0; u2 < 8; ++u2) {
        const int* i3 = usu_3 + ((size_t)p * 8 + u2) * 16;
        float sS0 = 0.f, sS1 = 0.f; int cnt = 0;
#pragma unroll
        for (int t = 0; t < 16; t += 2) {
            int id0 = i3[t], id1 = i3[t + 1];
            cnt += (id0 != 0) + (id1 != 0);
            sS0 += E_s[(size_t)id0 * 64 + lane];   // E_s[0] == 0
            sS1 += E_s[(size_t)id1 * 64 + lane];
        }
        float wgt = cnt > 0 ? 1.f / ((float)cnt + 1e-8f) : 0.f;
        sE += leakyf(dot1((sS0 + sS1) * wgt, w3)); // eu2 row, summed over u2
    }
    int cnt2 = 0;
    const int* m2 = usu_2 + (size_t)p * 8;
#pragma unroll
    for (int u2 = 0; u2 < 8; ++u2) cnt2 += (m2[u2] != 0);
    float wgt2 = cnt2 > 0 ? 1.f / ((float)cnt2 + 1e-8f) : 0.f;
    float A2 = sE * wgt2;
    float u1e = E_s[(size_t)usu_1[p] * 64 + lane];
    float w1[64], w2[64];
    load_wrow(w1, W21u, lane);
    load_wrow(w2, W22u, lane);
    es1[(size_t)p * 64 + lane] = leakyf(dot2(A2 + u1e, A2 * u1e, w1, w2));
}

// ---- usu final + dot with emb_dise ----
// rows = B = 1024; one wave per row
__global__ __launch_bounds__(256) void k_fin(
    const float* __restrict__ W1u, const int* __restrict__ usu_1,
    const float* __restrict__ es1, const float* __restrict__ emb_dise,
    float* __restrict__ out)
{
    const int lane = threadIdx.x & 63;
    const int b    = rfl((int)((blockIdx.x * blockDim.x + threadIdx.x) >> 6)); // 0..1023
    float w1[64];
    load_wrow(w1, W1u, lane);
    float sE0 = 0.f, sE1 = 0.f; int cnt = 0;
#pragma unroll
    for (int u1 = 0; u1 < 8; u1 += 2) {
        sE0 += es1[(size_t)(b * 8 + u1) * 64 + lane];
        sE1 += es1[(size_t)(b * 8 + u1 + 1) * 64 + lane];
        cnt += (usu_1[b * 8 + u1] != 0) + (usu_1[b * 8 + u1 + 1] != 0);
    }
    float wgt = cnt > 0 ? 1.f / ((float)cnt + 1e-8f) : 0.f;
    float eu = leakyf(dot1((sE0 + sE1) * wgt, w1));    // emb_user element
    float pr = eu * emb_dise[(size_t)b * 64 + lane];
#pragma unroll
    for (int off = 32; off > 0; off >>= 1) pr += __shfl_down(pr, off, 64);
    if (lane == 0) out[b] = pr;
}

extern "C" void kernel_launch(void* const* d_in, const int* in_sizes, int n_in,
                              void* d_out, int out_size, void* d_ws, size_t ws_size,
                              hipStream_t stream) {
    const float* E_s  = (const float*)d_in[0];
    const float* E_d  = (const float*)d_in[1];
    const float* W_dsd_21 = (const float*)d_in[2];
    const float* W_dsd_22 = (const float*)d_in[3];
    const float* W_dsd_11 = (const float*)d_in[4];
    const float* W_dsd_12 = (const float*)d_in[5];
    const float* W_usu_3  = (const float*)d_in[6];
    const float* W_usu_21 = (const float*)d_in[7];
    const float* W_usu_22 = (const float*)d_in[8];
    const float* W_usu_1  = (const float*)d_in[9];
    const int* label = (const int*)d_in[10];
    const int* dsd_1 = (const int*)d_in[11];
    const int* dsd_2 = (const int*)d_in[12];
    const int* usu_1 = (const int*)d_in[13];
    const int* usu_2 = (const int*)d_in[14];
    const int* usu_3 = (const int*)d_in[15];
    float* out = (float*)d_out;

    // scratch layout (all fp32): emb_s1 [8192*64], emb_dise [1024*64], es1 [8192*64]
    float* emb_s1   = (float*)d_ws;
    float* emb_dise = emb_s1 + 8192 * 64;
    float* es1      = emb_dise + 1024 * 64;

    k_dsd1<<<2048, 256, 0, stream>>>(E_s, E_d, W_dsd_21, W_dsd_22, dsd_1, dsd_2, emb_s1);
    k_dsd2<<<256, 256, 0, stream>>>(E_d, W_dsd_11, W_dsd_12, label, dsd_1, emb_s1, emb_dise);
    k_usu<<<2048, 256, 0, stream>>>(E_s, W_usu_3, W_usu_21, W_usu_22, usu_1, usu_2, usu_3, es1);
    k_fin<<<256, 256, 0, stream>>>(W_usu_1, usu_1, es1, emb_dise, out);
}

// Round 3
// 175.396 us; speedup vs baseline: 1.1104x; 1.1104x over previous
//
#include <hip/hip_runtime.h>

// HGNN forward, MI355X. fp32 throughout.
// R3: weights staged coalesced into LDS (XOR-swizzled rows), w3 pinned in
// VGPRs, dsd1+dsd2 merged (emb_s1 in LDS), usu+fin merged (es1 in LDS).
// Rationale: R1/R2 re-loaded weight rows from global per use; lane-strided
// (256B) weight loads touch 64 cache lines per instruction and saturate the
// per-CU vmem pipe (VALUBusy 28%, occupancy-insensitive).

__device__ __forceinline__ int rfl(int v) { return __builtin_amdgcn_readfirstlane(v); }
__device__ __forceinline__ float bcastf(float v, int l) {
    return __int_as_float(__builtin_amdgcn_readlane(__float_as_int(v), l));
}
__device__ __forceinline__ float leakyf(float x) { return x >= 0.f ? x : 0.2f * x; }

// Swizzled LDS weight layout: element [j][k] lives at float4 index
// 16*j + (((k>>2) + j) & 15)   (i.e. dword 64*j + 4*((k/4 + j)&15) + k%4).
// Row reads (lane=j) then spread over all 32 banks: 8 dwords/bank = LDS min.
__device__ __forceinline__ void stage_w(float* dst, const float* __restrict__ W, int tid) {
#pragma unroll
    for (int c = 0; c < 4; ++c) {
        int f4 = c * 256 + tid;          // 0..1023 float4s, coalesced global read
        int j = f4 >> 4, g = f4 & 15;
        float4 v = reinterpret_cast<const float4*>(W)[f4];
        reinterpret_cast<float4*>(dst)[(j << 4) + ((g + j) & 15)] = v;
    }
}

// out_j = sum_k x[k]*w[j][k], w pinned in registers
__device__ __forceinline__ float dot1_reg(float x, const float (&w)[64]) {
    float a0 = 0.f, a1 = 0.f, a2 = 0.f, a3 = 0.f;
#pragma unroll
    for (int k = 0; k < 64; k += 4) {
        a0 = fmaf(bcastf(x, k + 0), w[k + 0], a0);
        a1 = fmaf(bcastf(x, k + 1), w[k + 1], a1);
        a2 = fmaf(bcastf(x, k + 2), w[k + 2], a2);
        a3 = fmaf(bcastf(x, k + 3), w[k + 3], a3);
    }
    return (a0 + a1) + (a2 + a3);
}

// out_j = sum_k x[k]*w[j][k], w in swizzled LDS
__device__ __forceinline__ float dot1_lds(float x, const float* w, int lane) {
    float a0 = 0.f, a1 = 0.f, a2 = 0.f, a3 = 0.f;
#pragma unroll
    for (int g = 0; g < 16; ++g) {
        float4 c = reinterpret_cast<const float4*>(w)[(lane << 4) + ((g + lane) & 15)];
        int k = 4 * g;
        a0 = fmaf(bcastf(x, k + 0), c.x, a0);
        a1 = fmaf(bcastf(x, k + 1), c.y, a1);
        a2 = fmaf(bcastf(x, k + 2), c.z, a2);
        a3 = fmaf(bcastf(x, k + 3), c.w, a3);
    }
    return (a0 + a1) + (a2 + a3);
}

// out_j = sum_k xs[k]*w1[j][k] + xm[k]*w2[j][k], w1/w2 in swizzled LDS
__device__ __forceinline__ float dot2_lds(float xs, float xm,
                                          const float* w1, const float* w2, int lane) {
    float a0 = 0.f, a1 = 0.f, a2 = 0.f, a3 = 0.f;
#pragma unroll
    for (int g = 0; g < 16; ++g) {
        int f4 = (lane << 4) + ((g + lane) & 15);
        float4 c1 = reinterpret_cast<const float4*>(w1)[f4];
        float4 c2 = reinterpret_cast<const float4*>(w2)[f4];
        int k = 4 * g;
        float s0 = bcastf(xs, k + 0), s1 = bcastf(xs, k + 1);
        float s2 = bcastf(xs, k + 2), s3 = bcastf(xs, k + 3);
        float m0 = bcastf(xm, k + 0), m1 = bcastf(xm, k + 1);
        float m2 = bcastf(xm, k + 2), m3 = bcastf(xm, k + 3);
        a0 = fmaf(s0, c1.x, a0); a1 = fmaf(m0, c2.x, a1);
        a2 = fmaf(s1, c1.y, a2); a3 = fmaf(m1, c2.y, a3);
        a0 = fmaf(s2, c1.z, a0); a1 = fmaf(m2, c2.z, a1);
        a2 = fmaf(s3, c1.w, a2); a3 = fmaf(m3, c2.w, a3);
    }
    return (a0 + a1) + (a2 + a3);
}

// ---- dsd: one block per batch b. Phase1: 4 waves x 2 rows -> emb_s1 (LDS).
// Phase2: re-stage W11/W12, wave0 computes emb_dise[b]. LDS 34.8 KB -> 4 blk/CU.
__global__ __launch_bounds__(256, 4) void k_dsd(
    const float* __restrict__ E_s, const float* __restrict__ E_d,
    const float* __restrict__ W21, const float* __restrict__ W22,
    const float* __restrict__ W11, const float* __restrict__ W12,
    const int* __restrict__ label, const int* __restrict__ dsd_1,
    const int* __restrict__ dsd_2, float* __restrict__ emb_dise)
{
    __shared__ float sm[4096 * 2 + 512];
    float* sW1 = sm;            // W21, later W11
    float* sW2 = sm + 4096;     // W22, later W12
    float* sS1 = sm + 8192;     // emb_s1: 8 rows x 64
    const int tid = threadIdx.x, lane = tid & 63, w = rfl(tid >> 6), b = blockIdx.x;

    stage_w(sW1, W21, tid);
    stage_w(sW2, W22, tid);
    __syncthreads();

#pragma unroll
    for (int r = 0; r < 2; ++r) {
        int row = b * 8 + w * 2 + r;
        int is = dsd_1[row];
        float es = E_s[(size_t)is * 64 + lane];
        const int* d2 = dsd_2 + row * 8;
        float sA = 0.f; int cnt = 0;
#pragma unroll
        for (int h = 0; h < 8; ++h) {
            int id = d2[h];
            cnt += (id != 0);
            sA += E_d[(size_t)id * 64 + lane];   // E_d[0] == 0
        }
        float wgt = cnt > 0 ? 1.f / ((float)cnt + 1e-8f) : 0.f;
        float A = sA * wgt;
        sS1[(w * 2 + r) * 64 + lane] = leakyf(dot2_lds(A + es, A * es, sW1, sW2, lane));
    }
    __syncthreads();
    stage_w(sW1, W11, tid);
    stage_w(sW2, W12, tid);
    __syncthreads();

    if (w == 0) {
        float sE = 0.f; int cnt = 0;
        const int* d1 = dsd_1 + b * 8;
#pragma unroll
        for (int h = 0; h < 8; ++h) {
            sE += sS1[h * 64 + lane];
            cnt += (d1[h] != 0);
        }
        float wgt = cnt > 0 ? 1.f / ((float)cnt + 1e-8f) : 0.f;
        float A3 = sE * wgt;
        float td = E_d[(size_t)label[b] * 64 + lane];
        emb_dise[(size_t)b * 64 + lane] = leakyf(dot2_lds(A3 + td, A3 * td, sW1, sW2, lane));
    }
}

// ---- usu + fin: one block per batch b. w3 pinned in VGPRs; W1u re-staged
// over W3's LDS slot; es1 in LDS; wave0 does the final avg+dot+score.
// LDS 51.2 KB -> 3 blk/CU.
__global__ __launch_bounds__(256, 3) void k_usu(
    const float* __restrict__ E_s,
    const float* __restrict__ W3, const float* __restrict__ W21u,
    const float* __restrict__ W22u, const float* __restrict__ W1u,
    const int* __restrict__ usu_1, const int* __restrict__ usu_2,
    const int* __restrict__ usu_3,
    const float* __restrict__ emb_dise, float* __restrict__ out)
{
    __shared__ float sm[4096 * 3 + 512];
    float* sW3 = sm;            // W3, later W1u
    float* sW1 = sm + 4096;     // W21u
    float* sW2 = sm + 8192;     // W22u
    float* sE1 = sm + 12288;    // es1: 8 rows x 64
    const int tid = threadIdx.x, lane = tid & 63, w = rfl(tid >> 6), b = blockIdx.x;

    stage_w(sW3, W3, tid);
    stage_w(sW1, W21u, tid);
    stage_w(sW2, W22u, tid);
    __syncthreads();

    float w3[64];
#pragma unroll
    for (int g = 0; g < 16; ++g) {
        float4 v = reinterpret_cast<const float4*>(sW3)[(lane << 4) + ((g + lane) & 15)];
        w3[4 * g + 0] = v.x; w3[4 * g + 1] = v.y;
        w3[4 * g + 2] = v.z; w3[4 * g + 3] = v.w;
    }
    __syncthreads();               // all waves done pinning w3
    stage_w(sW3, W1u, tid);        // overwrite W3 slot; read only after next sync

#pragma unroll
    for (int r = 0; r < 2; ++r) {
        int p = b * 8 + w * 2 + r;
        float sE = 0.f;
        const int* i3b = usu_3 + (size_t)p * 128;
#pragma unroll
        for (int u2 = 0; u2 < 8; ++u2) {
            const int* i3 = i3b + u2 * 16;
            float s0 = 0.f, s1 = 0.f; int cnt = 0;
#pragma unroll
            for (int t = 0; t < 16; t += 2) {
                int id0 = i3[t], id1 = i3[t + 1];
                cnt += (id0 != 0) + (id1 != 0);
                s0 += E_s[(size_t)id0 * 64 + lane];   // E_s[0] == 0
                s1 += E_s[(size_t)id1 * 64 + lane];
            }
            float wgt = cnt > 0 ? 1.f / ((float)cnt + 1e-8f) : 0.f;
            sE += leakyf(dot1_reg((s0 + s1) * wgt, w3));
        }
        const int* m2 = usu_2 + p * 8; int cnt2 = 0;
#pragma unroll
        for (int u2 = 0; u2 < 8; ++u2) cnt2 += (m2[u2] != 0);
        float wgt2 = cnt2 > 0 ? 1.f / ((float)cnt2 + 1e-8f) : 0.f;
        float A2 = sE * wgt2;
        float u1e = E_s[(size_t)usu_1[p] * 64 + lane];
        sE1[(w * 2 + r) * 64 + lane] = leakyf(dot2_lds(A2 + u1e, A2 * u1e, sW1, sW2, lane));
    }
    __syncthreads();

    if (w == 0) {
        float sE = 0.f; int cnt = 0;
        const int* u1i = usu_1 + b * 8;
#pragma unroll
        for (int h = 0; h < 8; ++h) {
            sE += sE1[h * 64 + lane];
            cnt += (u1i[h] != 0);
        }
        float wgt = cnt > 0 ? 1.f / ((float)cnt + 1e-8f) : 0.f;
        float eu = leakyf(dot1_lds(sE * wgt, sW3, lane));   // sW3 now holds W1u
        float pr = eu * emb_dise[(size_t)b * 64 + lane];
#pragma unroll
        for (int off = 32; off > 0; off >>= 1) pr += __shfl_down(pr, off, 64);
        if (lane == 0) out[b] = pr;
    }
}

extern "C" void kernel_launch(void* const* d_in, const int* in_sizes, int n_in,
                              void* d_out, int out_size, void* d_ws, size_t ws_size,
                              hipStream_t stream) {
    const float* E_s  = (const float*)d_in[0];
    const float* E_d  = (const float*)d_in[1];
    const float* W_dsd_21 = (const float*)d_in[2];
    const float* W_dsd_22 = (const float*)d_in[3];
    const float* W_dsd_11 = (const float*)d_in[4];
    const float* W_dsd_12 = (const float*)d_in[5];
    const float* W_usu_3  = (const float*)d_in[6];
    const float* W_usu_21 = (const float*)d_in[7];
    const float* W_usu_22 = (const float*)d_in[8];
    const float* W_usu_1  = (const float*)d_in[9];
    const int* label = (const int*)d_in[10];
    const int* dsd_1 = (const int*)d_in[11];
    const int* dsd_2 = (const int*)d_in[12];
    const int* usu_1 = (const int*)d_in[13];
    const int* usu_2 = (const int*)d_in[14];
    const int* usu_3 = (const int*)d_in[15];
    float* out = (float*)d_out;

    float* emb_dise = (float*)d_ws;   // 1024 x 64 fp32

    k_dsd<<<1024, 256, 0, stream>>>(E_s, E_d, W_dsd_21, W_dsd_22, W_dsd_11, W_dsd_12,
                                    label, dsd_1, dsd_2, emb_dise);
    k_usu<<<1024, 256, 0, stream>>>(E_s, W_usu_3, W_usu_21, W_usu_22, W_usu_1,
                                    usu_1, usu_2, usu_3, emb_dise, out);
}

// Round 4
// 163.686 us; speedup vs baseline: 1.1899x; 1.0715x over previous
//
#include <hip/hip_runtime.h>
#include <hip/hip_bf16.h>

// HGNN forward, MI355X.
// R4: usu stage-1 (the W3 transform, ~60% of R3's VALU) moved to MFMA
// (16x16x32 bf16) with hi/lo bf16 split for fp32-grade precision
// (x*w ~ xh*wh + xh*wl + xl*wh; rel err ~2^-17). Gathered per-(p,u2)
// averaged vectors -> LDS X (64x64, rows padded to 72 shorts = 144B:
// 16B-aligned b128 frags, perfectly bank-balanced). u2-reduction done in
// MFMA C-layout (sum 4 regs + shfl_xor 16). Stage-2 + final keep R3's
// verified fp32 LDS-dot path. k_dsd unchanged from R3 (verified).

typedef __attribute__((ext_vector_type(8))) short short8;
typedef __attribute__((ext_vector_type(4))) float f32x4;

__device__ __forceinline__ int rfl(int v) { return __builtin_amdgcn_readfirstlane(v); }
__device__ __forceinline__ float bcastf(float v, int l) {
    return __int_as_float(__builtin_amdgcn_readlane(__float_as_int(v), l));
}
__device__ __forceinline__ float leakyf(float x) { return x >= 0.f ? x : 0.2f * x; }

__device__ __forceinline__ unsigned short bf16bits(float x) {
    __hip_bfloat16 h = __float2bfloat16(x);
    return __builtin_bit_cast(unsigned short, h);
}
__device__ __forceinline__ float bf16tof(unsigned short s) {
    __hip_bfloat16 h = __builtin_bit_cast(__hip_bfloat16, s);
    return __bfloat162float(h);
}

// Swizzled LDS fp32 weight layout (R3-verified): element [j][k] at float4
// index 16*j + (((k>>2)+j)&15).
__device__ __forceinline__ void stage_w(float* dst, const float* __restrict__ W, int tid) {
#pragma unroll
    for (int c = 0; c < 4; ++c) {
        int f4 = c * 256 + tid;
        int j = f4 >> 4, g = f4 & 15;
        float4 v = reinterpret_cast<const float4*>(W)[f4];
        reinterpret_cast<float4*>(dst)[(j << 4) + ((g + j) & 15)] = v;
    }
}

__device__ __forceinline__ float dot1_lds(float x, const float* w, int lane) {
    float a0 = 0.f, a1 = 0.f, a2 = 0.f, a3 = 0.f;
#pragma unroll
    for (int g = 0; g < 16; ++g) {
        float4 c = reinterpret_cast<const float4*>(w)[(lane << 4) + ((g + lane) & 15)];
        int k = 4 * g;
        a0 = fmaf(bcastf(x, k + 0), c.x, a0);
        a1 = fmaf(bcastf(x, k + 1), c.y, a1);
        a2 = fmaf(bcastf(x, k + 2), c.z, a2);
        a3 = fmaf(bcastf(x, k + 3), c.w, a3);
    }
    return (a0 + a1) + (a2 + a3);
}

__device__ __forceinline__ float dot2_lds(float xs, float xm,
                                          const float* w1, const float* w2, int lane) {
    float a0 = 0.f, a1 = 0.f, a2 = 0.f, a3 = 0.f;
#pragma unroll
    for (int g = 0; g < 16; ++g) {
        int f4 = (lane << 4) + ((g + lane) & 15);
        float4 c1 = reinterpret_cast<const float4*>(w1)[f4];
        float4 c2 = reinterpret_cast<const float4*>(w2)[f4];
        int k = 4 * g;
        float s0 = bcastf(xs, k + 0), s1 = bcastf(xs, k + 1);
        float s2 = bcastf(xs, k + 2), s3 = bcastf(xs, k + 3);
        float m0 = bcastf(xm, k + 0), m1 = bcastf(xm, k + 1);
        float m2 = bcastf(xm, k + 2), m3 = bcastf(xm, k + 3);
        a0 = fmaf(s0, c1.x, a0); a1 = fmaf(m0, c2.x, a1);
        a2 = fmaf(s1, c1.y, a2); a3 = fmaf(m1, c2.y, a3);
        a0 = fmaf(s2, c1.z, a0); a1 = fmaf(m2, c2.z, a1);
        a2 = fmaf(s3, c1.w, a2); a3 = fmaf(m3, c2.w, a3);
    }
    return (a0 + a1) + (a2 + a3);
}

// ---- dsd: unchanged from R3 (verified) ----
__global__ __launch_bounds__(256, 4) void k_dsd(
    const float* __restrict__ E_s, const float* __restrict__ E_d,
    const float* __restrict__ W21, const float* __restrict__ W22,
    const float* __restrict__ W11, const float* __restrict__ W12,
    const int* __restrict__ label, const int* __restrict__ dsd_1,
    const int* __restrict__ dsd_2, float* __restrict__ emb_dise)
{
    __shared__ float sm[4096 * 2 + 512];
    float* sW1 = sm;
    float* sW2 = sm + 4096;
    float* sS1 = sm + 8192;
    const int tid = threadIdx.x, lane = tid & 63, w = rfl(tid >> 6), b = blockIdx.x;

    stage_w(sW1, W21, tid);
    stage_w(sW2, W22, tid);
    __syncthreads();

#pragma unroll
    for (int r = 0; r < 2; ++r) {
        int row = b * 8 + w * 2 + r;
        int is = dsd_1[row];
        float es = E_s[(size_t)is * 64 + lane];
        const int* d2 = dsd_2 + row * 8;
        float sA = 0.f; int cnt = 0;
#pragma unroll
        for (int h = 0; h < 8; ++h) {
            int id = d2[h];
            cnt += (id != 0);
            sA += E_d[(size_t)id * 64 + lane];
        }
        float wgt = cnt > 0 ? 1.f / ((float)cnt + 1e-8f) : 0.f;
        float A = sA * wgt;
        sS1[(w * 2 + r) * 64 + lane] = leakyf(dot2_lds(A + es, A * es, sW1, sW2, lane));
    }
    __syncthreads();
    stage_w(sW1, W11, tid);
    stage_w(sW2, W12, tid);
    __syncthreads();

    if (w == 0) {
        float sE = 0.f; int cnt = 0;
        const int* d1 = dsd_1 + b * 8;
#pragma unroll
        for (int h = 0; h < 8; ++h) {
            sE += sS1[h * 64 + lane];
            cnt += (d1[h] != 0);
        }
        float wgt = cnt > 0 ? 1.f / ((float)cnt + 1e-8f) : 0.f;
        float A3 = sE * wgt;
        float td = E_d[(size_t)label[b] * 64 + lane];
        emb_dise[(size_t)b * 64 + lane] = leakyf(dot2_lds(A3 + td, A3 * td, sW1, sW2, lane));
    }
}

// ---- usu: one block per b. Gather->LDS X (bf16 hi/lo), MFMA W3 transform,
// C-layout u2-reduction, fp32 stage-2 + final. LDS 72 KB -> 2 blk/CU. ----
#define XP 72   // X/W3 row pitch in shorts (144 B: 16B-aligned, bank-balanced)
__global__ __launch_bounds__(256, 2) void k_usu(
    const float* __restrict__ E_s,
    const float* __restrict__ W3, const float* __restrict__ W21u,
    const float* __restrict__ W22u, const float* __restrict__ W1u,
    const int* __restrict__ usu_1, const int* __restrict__ usu_2,
    const int* __restrict__ usu_3,
    const float* __restrict__ emb_dise, float* __restrict__ out)
{
    __shared__ float4 smraw[73728 / 16];
    unsigned short* sXh = (unsigned short*)smraw;     // 64 x 72 bf16
    unsigned short* sXl = sXh + 64 * XP;
    unsigned short* sW3h = sXl + 64 * XP;
    unsigned short* sW3l = sW3h + 64 * XP;
    float* sW21 = (float*)(sW3l + 64 * XP);           // fp32 swizzled
    float* sW22 = sW21 + 4096;
    float* sA2  = sW22 + 4096;                        // 8 x 64 fp32
    float* sES1 = sA2 + 512;                          // 8 x 64 fp32

    const int tid = threadIdx.x, lane = tid & 63, w = rfl(tid >> 6), b = blockIdx.x;

    // Phase 0: convert W3 -> bf16 hi/lo in LDS; stage W21u/W22u fp32.
    {
        int row = tid >> 2, c0 = (tid & 3) << 4;
        const float* src = W3 + row * 64 + c0;
#pragma unroll
        for (int i = 0; i < 16; ++i) {
            float v = src[i];
            unsigned short h = bf16bits(v);
            sW3h[row * XP + c0 + i] = h;
            sW3l[row * XP + c0 + i] = bf16bits(v - bf16tof(h));
        }
    }
    stage_w(sW21, W21u, tid);
    stage_w(sW22, W22u, tid);
    __syncthreads();

    // Phase 1: gather + masked-avg 16 E_s rows per q=(p,u2); wave w owns
    // local rows w*16 .. w*16+15. Store fp32 -> bf16 hi/lo into X.
    for (int i = 0; i < 16; ++i) {
        int ql = w * 16 + i;
        const int* i3 = usu_3 + ((size_t)(b * 64 + ql)) * 16;
        float s0 = 0.f, s1 = 0.f; int cnt = 0;
#pragma unroll
        for (int t = 0; t < 16; t += 2) {
            int id0 = i3[t], id1 = i3[t + 1];
            cnt += (id0 != 0) + (id1 != 0);
            s0 += E_s[(size_t)id0 * 64 + lane];   // E_s[0] == 0
            s1 += E_s[(size_t)id1 * 64 + lane];
        }
        float wgt = cnt > 0 ? 1.f / ((float)cnt + 1e-8f) : 0.f;
        float x = (s0 + s1) * wgt;
        unsigned short h = bf16bits(x);
        sXh[ql * XP + lane] = h;
        sXl[ql * XP + lane] = bf16bits(x - bf16tof(h));
    }
    __syncthreads();

    // Phase 2: Y = leaky(X @ W3^T) via MFMA; reduce u2-groups in C-layout.
    // A-frag: A[m=lane&15][k=quad*8+j]; B-frag: B[k=quad*8+j][n=lane&15]
    // with B[k][n]=W3[n][k] (row-read of W3). C/D: col=lane&15, row=quad*4+r.
    const int m = lane & 15, quad = lane >> 4;
    short8 ah0, ah1, al0, al1;
    {
        const int base = (16 * w + m) * XP + quad * 8;
        ah0 = *(const short8*)(sXh + base);
        ah1 = *(const short8*)(sXh + base + 32);
        al0 = *(const short8*)(sXl + base);
        al1 = *(const short8*)(sXl + base + 32);
    }
    int cp0 = 0, cp1 = 0;
    {
        const int* m2 = usu_2 + (b * 8 + 2 * w) * 8;
#pragma unroll
        for (int u = 0; u < 8; ++u) { cp0 += (m2[u] != 0); cp1 += (m2[u + 8] != 0); }
    }
    float wg0 = cp0 > 0 ? 1.f / ((float)cp0 + 1e-8f) : 0.f;
    float wg1 = cp1 > 0 ? 1.f / ((float)cp1 + 1e-8f) : 0.f;
#pragma unroll
    for (int J = 0; J < 4; ++J) {
        const int wb = (16 * J + m) * XP + quad * 8;
        short8 bh0 = *(const short8*)(sW3h + wb);
        short8 bh1 = *(const short8*)(sW3h + wb + 32);
        short8 bl0 = *(const short8*)(sW3l + wb);
        short8 bl1 = *(const short8*)(sW3l + wb + 32);
        f32x4 acc = {0.f, 0.f, 0.f, 0.f};
        acc = __builtin_amdgcn_mfma_f32_16x16x32_bf16(ah0, bh0, acc, 0, 0, 0);
        acc = __builtin_amdgcn_mfma_f32_16x16x32_bf16(ah1, bh1, acc, 0, 0, 0);
        acc = __builtin_amdgcn_mfma_f32_16x16x32_bf16(ah0, bl0, acc, 0, 0, 0);
        acc = __builtin_amdgcn_mfma_f32_16x16x32_bf16(ah1, bl1, acc, 0, 0, 0);
        acc = __builtin_amdgcn_mfma_f32_16x16x32_bf16(al0, bh0, acc, 0, 0, 0);
        acc = __builtin_amdgcn_mfma_f32_16x16x32_bf16(al1, bh1, acc, 0, 0, 0);
        // leaky per element, then sum this lane's 4 rows + partner quad's 4:
        // quads {0,1} -> rows 0-7 (p0 = 2w), quads {2,3} -> rows 8-15 (p1).
        float t = leakyf(acc[0]) + leakyf(acc[1]) + leakyf(acc[2]) + leakyf(acc[3]);
        t += __shfl_xor(t, 16, 64);
        if (quad == 0) sA2[(2 * w + 0) * 64 + J * 16 + m] = t * wg0;
        if (quad == 2) sA2[(2 * w + 1) * 64 + J * 16 + m] = t * wg1;
    }

    // Phase 3: stage-2 fp32 (wave w owns p = 2w, 2w+1; reads only own sA2 rows).
#pragma unroll
    for (int pp = 0; pp < 2; ++pp) {
        int p = 2 * w + pp;
        float x = sA2[p * 64 + lane];
        float u1e = E_s[(size_t)usu_1[b * 8 + p] * 64 + lane];
        sES1[p * 64 + lane] = leakyf(dot2_lds(x + u1e, x * u1e, sW21, sW22, lane));
    }
    __syncthreads();
    stage_w((float*)sXh, W1u, tid);   // X region (18 KB) free now; W1u fp32 swizzled
    __syncthreads();

    if (w == 0) {
        float sE = 0.f; int cnt = 0;
        const int* u1i = usu_1 + b * 8;
#pragma unroll
        for (int h = 0; h < 8; ++h) {
            sE += sES1[h * 64 + lane];
            cnt += (u1i[h] != 0);
        }
        float wgt = cnt > 0 ? 1.f / ((float)cnt + 1e-8f) : 0.f;
        float eu = leakyf(dot1_lds(sE * wgt, (float*)sXh, lane));
        float pr = eu * emb_dise[(size_t)b * 64 + lane];
#pragma unroll
        for (int off = 32; off > 0; off >>= 1) pr += __shfl_down(pr, off, 64);
        if (lane == 0) out[b] = pr;
    }
}

extern "C" void kernel_launch(void* const* d_in, const int* in_sizes, int n_in,
                              void* d_out, int out_size, void* d_ws, size_t ws_size,
                              hipStream_t stream) {
    const float* E_s  = (const float*)d_in[0];
    const float* E_d  = (const float*)d_in[1];
    const float* W_dsd_21 = (const float*)d_in[2];
    const float* W_dsd_22 = (const float*)d_in[3];
    const float* W_dsd_11 = (const float*)d_in[4];
    const float* W_dsd_12 = (const float*)d_in[5];
    const float* W_usu_3  = (const float*)d_in[6];
    const float* W_usu_21 = (const float*)d_in[7];
    const float* W_usu_22 = (const float*)d_in[8];
    const float* W_usu_1  = (const float*)d_in[9];
    const int* label = (const int*)d_in[10];
    const int* dsd_1 = (const int*)d_in[11];
    const int* dsd_2 = (const int*)d_in[12];
    const int* usu_1 = (const int*)d_in[13];
    const int* usu_2 = (const int*)d_in[14];
    const int* usu_3 = (const int*)d_in[15];
    float* out = (float*)d_out;

    float* emb_dise = (float*)d_ws;   // 1024 x 64 fp32

    k_dsd<<<1024, 256, 0, stream>>>(E_s, E_d, W_dsd_21, W_dsd_22, W_dsd_11, W_dsd_12,
                                    label, dsd_1, dsd_2, emb_dise);
    k_usu<<<1024, 256, 0, stream>>>(E_s, W_usu_3, W_usu_21, W_usu_22, W_usu_1,
                                    usu_1, usu_2, usu_3, emb_dise, out);
}

// Round 5
// 160.517 us; speedup vs baseline: 1.2134x; 1.0197x over previous
//
#include <hip/hip_runtime.h>
#include <hip/hip_bf16.h>

// HGNN forward, MI355X.
// R5: gathers dominated (98 MB fetch = 8 XCD x 12.8 MB E_s table @ 2.2 TB/s
// = k_usu's whole 45 us). Pre-convert E_s -> bf16 table (6.4 MB): halves
// lines/gather and doubles per-XCD L2 hit rate. dsd + usu fused in one
// launch (odd/even blocks) to overlap; tiny k_dot epilogue. MFMA stage-1
// with hi/lo bf16 split (R4-verified); u1e / stage-2 stay fp32.

typedef __attribute__((ext_vector_type(8))) short short8;
typedef __attribute__((ext_vector_type(8))) unsigned short ushort8;
typedef __attribute__((ext_vector_type(4))) float f32x4;

__device__ __forceinline__ int rfl(int v) { return __builtin_amdgcn_readfirstlane(v); }
__device__ __forceinline__ float bcastf(float v, int l) {
    return __int_as_float(__builtin_amdgcn_readlane(__float_as_int(v), l));
}
__device__ __forceinline__ float leakyf(float x) { return x >= 0.f ? x : 0.2f * x; }

__device__ __forceinline__ unsigned short bf16bits(float x) {
    __hip_bfloat16 h = __float2bfloat16(x);
    return __builtin_bit_cast(unsigned short, h);
}
__device__ __forceinline__ float bf16tof(unsigned short s) {
    __hip_bfloat16 h = __builtin_bit_cast(__hip_bfloat16, s);
    return __bfloat162float(h);
}

// Swizzled LDS fp32 weight layout (R3-verified): element [j][k] at float4
// index 16*j + (((k>>2)+j)&15).
__device__ __forceinline__ void stage_w(float* dst, const float* __restrict__ W, int tid) {
#pragma unroll
    for (int c = 0; c < 4; ++c) {
        int f4 = c * 256 + tid;
        int j = f4 >> 4, g = f4 & 15;
        float4 v = reinterpret_cast<const float4*>(W)[f4];
        reinterpret_cast<float4*>(dst)[(j << 4) + ((g + j) & 15)] = v;
    }
}

__device__ __forceinline__ float dot1_lds(float x, const float* w, int lane) {
    float a0 = 0.f, a1 = 0.f, a2 = 0.f, a3 = 0.f;
#pragma unroll
    for (int g = 0; g < 16; ++g) {
        float4 c = reinterpret_cast<const float4*>(w)[(lane << 4) + ((g + lane) & 15)];
        int k = 4 * g;
        a0 = fmaf(bcastf(x, k + 0), c.x, a0);
        a1 = fmaf(bcastf(x, k + 1), c.y, a1);
        a2 = fmaf(bcastf(x, k + 2), c.z, a2);
        a3 = fmaf(bcastf(x, k + 3), c.w, a3);
    }
    return (a0 + a1) + (a2 + a3);
}

__device__ __forceinline__ float dot2_lds(float xs, float xm,
                                          const float* w1, const float* w2, int lane) {
    float a0 = 0.f, a1 = 0.f, a2 = 0.f, a3 = 0.f;
#pragma unroll
    for (int g = 0; g < 16; ++g) {
        int f4 = (lane << 4) + ((g + lane) & 15);
        float4 c1 = reinterpret_cast<const float4*>(w1)[f4];
        float4 c2 = reinterpret_cast<const float4*>(w2)[f4];
        int k = 4 * g;
        float s0 = bcastf(xs, k + 0), s1 = bcastf(xs, k + 1);
        float s2 = bcastf(xs, k + 2), s3 = bcastf(xs, k + 3);
        float m0 = bcastf(xm, k + 0), m1 = bcastf(xm, k + 1);
        float m2 = bcastf(xm, k + 2), m3 = bcastf(xm, k + 3);
        a0 = fmaf(s0, c1.x, a0); a1 = fmaf(m0, c2.x, a1);
        a2 = fmaf(s1, c1.y, a2); a3 = fmaf(m1, c2.y, a3);
        a0 = fmaf(s2, c1.z, a0); a1 = fmaf(m2, c2.z, a1);
        a2 = fmaf(s3, c1.w, a2); a3 = fmaf(m3, c2.w, a3);
    }
    return (a0 + a1) + (a2 + a3);
}

// ---- E_s fp32 -> bf16 table (50001*64 = 3,200,064 elems, 8 per thread) ----
__global__ __launch_bounds__(256) void k_cvt(const float* __restrict__ E_s,
                                             unsigned short* __restrict__ T) {
    int t = blockIdx.x * 256 + threadIdx.x;
    if (t >= 400008) return;
    const float4* p = reinterpret_cast<const float4*>(E_s) + (size_t)t * 2;
    float4 a = p[0], b = p[1];
    ushort8 o;
    o[0] = bf16bits(a.x); o[1] = bf16bits(a.y); o[2] = bf16bits(a.z); o[3] = bf16bits(a.w);
    o[4] = bf16bits(b.x); o[5] = bf16bits(b.y); o[6] = bf16bits(b.z); o[7] = bf16bits(b.w);
    *(reinterpret_cast<ushort8*>(T) + t) = o;
}

#define XP 72   // X/W3 row pitch in shorts (144 B)

// ---- fused main: odd blocks = dsd(b), even blocks = usu(b), b = blockIdx>>1
__global__ __launch_bounds__(256, 2) void k_main(
    const float* __restrict__ E_s, const unsigned short* __restrict__ Ebf,
    const float* __restrict__ E_d,
    const float* __restrict__ W21, const float* __restrict__ W22,
    const float* __restrict__ W11, const float* __restrict__ W12,
    const float* __restrict__ W3, const float* __restrict__ W21u,
    const float* __restrict__ W22u, const float* __restrict__ W1u,
    const int* __restrict__ label, const int* __restrict__ dsd_1,
    const int* __restrict__ dsd_2, const int* __restrict__ usu_1,
    const int* __restrict__ usu_2, const int* __restrict__ usu_3,
    float* __restrict__ emb_dise, float* __restrict__ emb_user)
{
    __shared__ float4 smraw[73728 / 16];
    const int tid = threadIdx.x, lane = tid & 63, w = rfl(tid >> 6);
    const int b = blockIdx.x >> 1;

    if (blockIdx.x & 1) {
        // ================= dsd branch (R3/R4-verified) =================
        float* sW1 = (float*)smraw;
        float* sW2 = sW1 + 4096;
        float* sS1 = sW2 + 4096;

        stage_w(sW1, W21, tid);
        stage_w(sW2, W22, tid);
        __syncthreads();

#pragma unroll
        for (int r = 0; r < 2; ++r) {
            int row = b * 8 + w * 2 + r;
            int is = dsd_1[row];
            float es = E_s[(size_t)is * 64 + lane];
            const int* d2 = dsd_2 + row * 8;
            float sA = 0.f; int cnt = 0;
#pragma unroll
            for (int h = 0; h < 8; ++h) {
                int id = d2[h];
                cnt += (id != 0);
                sA += E_d[(size_t)id * 64 + lane];   // E_d[0] == 0
            }
            float wgt = cnt > 0 ? 1.f / ((float)cnt + 1e-8f) : 0.f;
            float A = sA * wgt;
            sS1[(w * 2 + r) * 64 + lane] = leakyf(dot2_lds(A + es, A * es, sW1, sW2, lane));
        }
        __syncthreads();
        stage_w(sW1, W11, tid);
        stage_w(sW2, W12, tid);
        __syncthreads();

        if (w == 0) {
            float sE = 0.f; int cnt = 0;
            const int* d1 = dsd_1 + b * 8;
#pragma unroll
            for (int h = 0; h < 8; ++h) {
                sE += sS1[h * 64 + lane];
                cnt += (d1[h] != 0);
            }
            float wgt = cnt > 0 ? 1.f / ((float)cnt + 1e-8f) : 0.f;
            float A3 = sE * wgt;
            float td = E_d[(size_t)label[b] * 64 + lane];
            emb_dise[(size_t)b * 64 + lane] = leakyf(dot2_lds(A3 + td, A3 * td, sW1, sW2, lane));
        }
    } else {
        // ================= usu branch =================
        unsigned short* sXh = (unsigned short*)smraw;     // 64 x 72 bf16
        unsigned short* sXl = sXh + 64 * XP;
        unsigned short* sW3h = sXl + 64 * XP;
        unsigned short* sW3l = sW3h + 64 * XP;
        float* sW21 = (float*)(sW3l + 64 * XP);
        float* sW22 = sW21 + 4096;
        float* sA2  = sW22 + 4096;
        float* sES1 = sA2 + 512;

        // Phase 0: W3 -> bf16 hi/lo in LDS; W21u/W22u fp32 swizzled.
        {
            int row = tid >> 2, c0 = (tid & 3) << 4;
            const float* src = W3 + row * 64 + c0;
#pragma unroll
            for (int i = 0; i < 16; ++i) {
                float v = src[i];
                unsigned short h = bf16bits(v);
                sW3h[row * XP + c0 + i] = h;
                sW3l[row * XP + c0 + i] = bf16bits(v - bf16tof(h));
            }
        }
        stage_w(sW21, W21u, tid);
        stage_w(sW22, W22u, tid);
        __syncthreads();

        // Phase 1: bf16-table gathers + masked-avg -> X (bf16 hi/lo).
        for (int i = 0; i < 16; ++i) {
            int ql = w * 16 + i;
            const int* i3 = usu_3 + ((size_t)(b * 64 + ql)) * 16;
            float s0 = 0.f, s1 = 0.f; int cnt = 0;
#pragma unroll
            for (int t = 0; t < 16; t += 2) {
                int id0 = i3[t], id1 = i3[t + 1];
                cnt += (id0 != 0) + (id1 != 0);
                s0 += bf16tof(Ebf[(size_t)id0 * 64 + lane]);   // Ebf[0] row == 0
                s1 += bf16tof(Ebf[(size_t)id1 * 64 + lane]);
            }
            float wgt = cnt > 0 ? 1.f / ((float)cnt + 1e-8f) : 0.f;
            float x = (s0 + s1) * wgt;
            unsigned short h = bf16bits(x);
            sXh[ql * XP + lane] = h;
            sXl[ql * XP + lane] = bf16bits(x - bf16tof(h));
        }
        __syncthreads();

        // Phase 2: Y = leaky(X @ W3^T) via MFMA; u2-reduction in C-layout.
        const int m = lane & 15, quad = lane >> 4;
        short8 ah0, ah1, al0, al1;
        {
            const int base = (16 * w + m) * XP + quad * 8;
            ah0 = *(const short8*)(sXh + base);
            ah1 = *(const short8*)(sXh + base + 32);
            al0 = *(const short8*)(sXl + base);
            al1 = *(const short8*)(sXl + base + 32);
        }
        int cp0 = 0, cp1 = 0;
        {
            const int* m2 = usu_2 + (b * 8 + 2 * w) * 8;
#pragma unroll
            for (int u = 0; u < 8; ++u) { cp0 += (m2[u] != 0); cp1 += (m2[u + 8] != 0); }
        }
        float wg0 = cp0 > 0 ? 1.f / ((float)cp0 + 1e-8f) : 0.f;
        float wg1 = cp1 > 0 ? 1.f / ((float)cp1 + 1e-8f) : 0.f;
#pragma unroll
        for (int J = 0; J < 4; ++J) {
            const int wb = (16 * J + m) * XP + quad * 8;
            short8 bh0 = *(const short8*)(sW3h + wb);
            short8 bh1 = *(const short8*)(sW3h + wb + 32);
            short8 bl0 = *(const short8*)(sW3l + wb);
            short8 bl1 = *(const short8*)(sW3l + wb + 32);
            f32x4 acc = {0.f, 0.f, 0.f, 0.f};
            acc = __builtin_amdgcn_mfma_f32_16x16x32_bf16(ah0, bh0, acc, 0, 0, 0);
            acc = __builtin_amdgcn_mfma_f32_16x16x32_bf16(ah1, bh1, acc, 0, 0, 0);
            acc = __builtin_amdgcn_mfma_f32_16x16x32_bf16(ah0, bl0, acc, 0, 0, 0);
            acc = __builtin_amdgcn_mfma_f32_16x16x32_bf16(ah1, bl1, acc, 0, 0, 0);
            acc = __builtin_amdgcn_mfma_f32_16x16x32_bf16(al0, bh0, acc, 0, 0, 0);
            acc = __builtin_amdgcn_mfma_f32_16x16x32_bf16(al1, bh1, acc, 0, 0, 0);
            float t = leakyf(acc[0]) + leakyf(acc[1]) + leakyf(acc[2]) + leakyf(acc[3]);
            t += __shfl_xor(t, 16, 64);
            if (quad == 0) sA2[(2 * w + 0) * 64 + J * 16 + m] = t * wg0;
            if (quad == 2) sA2[(2 * w + 1) * 64 + J * 16 + m] = t * wg1;
        }

        // Phase 3: stage-2 fp32 (same-wave cross-lane LDS, no barrier needed).
#pragma unroll
        for (int pp = 0; pp < 2; ++pp) {
            int p = 2 * w + pp;
            float x = sA2[p * 64 + lane];
            float u1e = E_s[(size_t)usu_1[b * 8 + p] * 64 + lane];
            sES1[p * 64 + lane] = leakyf(dot2_lds(x + u1e, x * u1e, sW21, sW22, lane));
        }
        __syncthreads();
        stage_w((float*)sXh, W1u, tid);   // X region free; W1u fp32 swizzled
        __syncthreads();

        if (w == 0) {
            float sE = 0.f; int cnt = 0;
            const int* u1i = usu_1 + b * 8;
#pragma unroll
            for (int h = 0; h < 8; ++h) {
                sE += sES1[h * 64 + lane];
                cnt += (u1i[h] != 0);
            }
            float wgt = cnt > 0 ? 1.f / ((float)cnt + 1e-8f) : 0.f;
            float eu = leakyf(dot1_lds(sE * wgt, (float*)sXh, lane));
            emb_user[(size_t)b * 64 + lane] = eu;
        }
    }
}

// ---- epilogue: out[b] = dot(emb_dise[b], emb_user[b]) ----
__global__ __launch_bounds__(256) void k_dot(const float* __restrict__ ed,
                                             const float* __restrict__ eu,
                                             float* __restrict__ out) {
    const int lane = threadIdx.x & 63;
    const int b = rfl((int)((blockIdx.x * blockDim.x + threadIdx.x) >> 6)); // 0..1023
    float pr = ed[(size_t)b * 64 + lane] * eu[(size_t)b * 64 + lane];
#pragma unroll
    for (int off = 32; off > 0; off >>= 1) pr += __shfl_down(pr, off, 64);
    if (lane == 0) out[b] = pr;
}

extern "C" void kernel_launch(void* const* d_in, const int* in_sizes, int n_in,
                              void* d_out, int out_size, void* d_ws, size_t ws_size,
                              hipStream_t stream) {
    const float* E_s  = (const float*)d_in[0];
    const float* E_d  = (const float*)d_in[1];
    const float* W_dsd_21 = (const float*)d_in[2];
    const float* W_dsd_22 = (const float*)d_in[3];
    const float* W_dsd_11 = (const float*)d_in[4];
    const float* W_dsd_12 = (const float*)d_in[5];
    const float* W_usu_3  = (const float*)d_in[6];
    const float* W_usu_21 = (const float*)d_in[7];
    const float* W_usu_22 = (const float*)d_in[8];
    const float* W_usu_1  = (const float*)d_in[9];
    const int* label = (const int*)d_in[10];
    const int* dsd_1 = (const int*)d_in[11];
    const int* dsd_2 = (const int*)d_in[12];
    const int* usu_1 = (const int*)d_in[13];
    const int* usu_2 = (const int*)d_in[14];
    const int* usu_3 = (const int*)d_in[15];
    float* out = (float*)d_out;

    // ws layout: Ebf [50001*64 bf16 = 6,400,128 B] | emb_dise [256 KB] | emb_user [256 KB]
    unsigned short* Ebf = (unsigned short*)d_ws;
    float* emb_dise = (float*)((char*)d_ws + 6400128);
    float* emb_user = emb_dise + 1024 * 64;

    k_cvt<<<1563, 256, 0, stream>>>(E_s, Ebf);
    k_main<<<2048, 256, 0, stream>>>(E_s, Ebf, E_d,
                                     W_dsd_21, W_dsd_22, W_dsd_11, W_dsd_12,
                                     W_usu_3, W_usu_21, W_usu_22, W_usu_1,
                                     label, dsd_1, dsd_2, usu_1, usu_2, usu_3,
                                     emb_dise, emb_user);
    k_dot<<<256, 256, 0, stream>>>(emb_dise, emb_user, out);
}

// Round 6
// 125.916 us; speedup vs baseline: 1.5468x; 1.2748x over previous
//
#include <hip/hip_runtime.h>
#include <hip/hip_bf16.h>

// HGNN forward, MI355X.
// R6: latency-bound fix. R4/R5 were gather-latency-bound (8 waves/CU, serial
// 16-iter gather loops; occupancy 12.5%). Now: 512-thread blocks, every phase
// wave-parallel (8 gather waves/block), LDS trimmed to 70 KB -> 2 blocks/CU
// = 16 waves/CU, ~256 outstanding gather loads/CU. usu blocks 0..1023 (1 b),
// dsd blocks 1024..1279 (4 b, fp32 path). bf16 E_s table (R5-verified,
// absmax 3e-5, 13x margin). MFMA hi/lo split for usu stage-1 (R4-verified).

typedef __attribute__((ext_vector_type(8))) short short8;
typedef __attribute__((ext_vector_type(8))) unsigned short ushort8;
typedef __attribute__((ext_vector_type(4))) float f32x4;

__device__ __forceinline__ int rfl(int v) { return __builtin_amdgcn_readfirstlane(v); }
__device__ __forceinline__ float bcastf(float v, int l) {
    return __int_as_float(__builtin_amdgcn_readlane(__float_as_int(v), l));
}
__device__ __forceinline__ float leakyf(float x) { return x >= 0.f ? x : 0.2f * x; }

__device__ __forceinline__ unsigned short bf16bits(float x) {
    __hip_bfloat16 h = __float2bfloat16(x);
    return __builtin_bit_cast(unsigned short, h);
}
__device__ __forceinline__ float bf16tof(unsigned short s) {
    __hip_bfloat16 h = __builtin_bit_cast(__hip_bfloat16, s);
    return __bfloat162float(h);
}

// Swizzled LDS fp32 weight layout (R3-verified): element [j][k] at float4
// index 16*j + (((k>>2)+j)&15). 512-thread stager: 2 float4 per thread.
__device__ __forceinline__ void stage_w512(float* dst, const float* __restrict__ W, int tid) {
#pragma unroll
    for (int c = 0; c < 2; ++c) {
        int f4 = c * 512 + tid;
        int j = f4 >> 4, g = f4 & 15;
        float4 v = reinterpret_cast<const float4*>(W)[f4];
        reinterpret_cast<float4*>(dst)[(j << 4) + ((g + j) & 15)] = v;
    }
}

__device__ __forceinline__ float dot1_lds(float x, const float* w, int lane) {
    float a0 = 0.f, a1 = 0.f, a2 = 0.f, a3 = 0.f;
#pragma unroll
    for (int g = 0; g < 16; ++g) {
        float4 c = reinterpret_cast<const float4*>(w)[(lane << 4) + ((g + lane) & 15)];
        int k = 4 * g;
        a0 = fmaf(bcastf(x, k + 0), c.x, a0);
        a1 = fmaf(bcastf(x, k + 1), c.y, a1);
        a2 = fmaf(bcastf(x, k + 2), c.z, a2);
        a3 = fmaf(bcastf(x, k + 3), c.w, a3);
    }
    return (a0 + a1) + (a2 + a3);
}

__device__ __forceinline__ float dot2_lds(float xs, float xm,
                                          const float* w1, const float* w2, int lane) {
    float a0 = 0.f, a1 = 0.f, a2 = 0.f, a3 = 0.f;
#pragma unroll
    for (int g = 0; g < 16; ++g) {
        int f4 = (lane << 4) + ((g + lane) & 15);
        float4 c1 = reinterpret_cast<const float4*>(w1)[f4];
        float4 c2 = reinterpret_cast<const float4*>(w2)[f4];
        int k = 4 * g;
        float s0 = bcastf(xs, k + 0), s1 = bcastf(xs, k + 1);
        float s2 = bcastf(xs, k + 2), s3 = bcastf(xs, k + 3);
        float m0 = bcastf(xm, k + 0), m1 = bcastf(xm, k + 1);
        float m2 = bcastf(xm, k + 2), m3 = bcastf(xm, k + 3);
        a0 = fmaf(s0, c1.x, a0); a1 = fmaf(m0, c2.x, a1);
        a2 = fmaf(s1, c1.y, a2); a3 = fmaf(m1, c2.y, a3);
        a0 = fmaf(s2, c1.z, a0); a1 = fmaf(m2, c2.z, a1);
        a2 = fmaf(s3, c1.w, a2); a3 = fmaf(m3, c2.w, a3);
    }
    return (a0 + a1) + (a2 + a3);
}

// ---- E_s fp32 -> bf16 table ----
__global__ __launch_bounds__(256) void k_cvt(const float* __restrict__ E_s,
                                             unsigned short* __restrict__ T) {
    int t = blockIdx.x * 256 + threadIdx.x;
    if (t >= 400008) return;
    const float4* p = reinterpret_cast<const float4*>(E_s) + (size_t)t * 2;
    float4 a = p[0], b = p[1];
    ushort8 o;
    o[0] = bf16bits(a.x); o[1] = bf16bits(a.y); o[2] = bf16bits(a.z); o[3] = bf16bits(a.w);
    o[4] = bf16bits(b.x); o[5] = bf16bits(b.y); o[6] = bf16bits(b.z); o[7] = bf16bits(b.w);
    *(reinterpret_cast<ushort8*>(T) + t) = o;
}

#define XP 72   // X/W3 row pitch in shorts (144 B: 16B-aligned, 2-way banks)

// LDS map (usu): sXh[64*72] sXl[64*72] sW3h[64*72] sW3l[64*72] (shorts)
//                sW21[4096] sW22[4096] sA2[512] (floats)  => 71680 B
// LDS map (dsd): sW1[4096] sW2[4096] (floats), sS1[32*64] floats => 40960 B
__global__ __launch_bounds__(512, 4) void k_main(
    const float* __restrict__ E_s, const unsigned short* __restrict__ Ebf,
    const float* __restrict__ E_d,
    const float* __restrict__ W21, const float* __restrict__ W22,
    const float* __restrict__ W11, const float* __restrict__ W12,
    const float* __restrict__ W3, const float* __restrict__ W21u,
    const float* __restrict__ W22u, const float* __restrict__ W1u,
    const int* __restrict__ label, const int* __restrict__ dsd_1,
    const int* __restrict__ dsd_2, const int* __restrict__ usu_1,
    const int* __restrict__ usu_2, const int* __restrict__ usu_3,
    float* __restrict__ emb_dise, float* __restrict__ emb_user)
{
    __shared__ float4 smraw[4480];   // 71680 B
    const int tid = threadIdx.x, lane = tid & 63, w = rfl(tid >> 6);

    if (blockIdx.x < 1024) {
        // ================= usu branch: one block per b, 8 waves =========
        const int b = blockIdx.x;
        unsigned short* sXh  = (unsigned short*)smraw;       // 64 x 72
        unsigned short* sXl  = sXh + 64 * XP;
        unsigned short* sW3h = sXl + 64 * XP;
        unsigned short* sW3l = sW3h + 64 * XP;
        float* sW21 = (float*)(sW3l + 64 * XP);
        float* sW22 = sW21 + 4096;
        float* sA2  = sW22 + 4096;                           // 8 x 64, reused as sES1

        // Phase 0: W3 -> bf16 hi/lo (8 elems/thread); W21u/W22u fp32 swizzled.
        {
            int row = tid >> 3, c0 = (tid & 7) << 3;
            const float* src = W3 + row * 64 + c0;
#pragma unroll
            for (int i = 0; i < 8; ++i) {
                float v = src[i];
                unsigned short h = bf16bits(v);
                sW3h[row * XP + c0 + i] = h;
                sW3l[row * XP + c0 + i] = bf16bits(v - bf16tof(h));
            }
        }
        stage_w512(sW21, W21u, tid);
        stage_w512(sW22, W22u, tid);

        // Phase 1: gather + masked-avg; wave w owns rows 8w..8w+7.
        for (int i = 0; i < 8; ++i) {
            int ql = w * 8 + i;
            const int* i3 = usu_3 + ((size_t)(b * 64 + ql)) * 16;
            float s0 = 0.f, s1 = 0.f; int cnt = 0;
#pragma unroll
            for (int t = 0; t < 16; t += 2) {
                int id0 = i3[t], id1 = i3[t + 1];
                cnt += (id0 != 0) + (id1 != 0);
                s0 += bf16tof(Ebf[(size_t)id0 * 64 + lane]);   // Ebf row 0 == 0
                s1 += bf16tof(Ebf[(size_t)id1 * 64 + lane]);
            }
            float wgt = cnt > 0 ? 1.f / ((float)cnt + 1e-8f) : 0.f;
            float x = (s0 + s1) * wgt;
            unsigned short h = bf16bits(x);
            sXh[ql * XP + lane] = h;
            sXl[ql * XP + lane] = bf16bits(x - bf16tof(h));
        }
        __syncthreads();

        // Phase 2: Y = leaky(X @ W3^T) via MFMA, wave-parallel:
        // wave w -> row-tile wt = w>>1, J in {2*(w&1), 2*(w&1)+1}.
        {
            const int m = lane & 15, quad = lane >> 4;
            const int wt = w >> 1, J0 = (w & 1) * 2;
            const int base = (16 * wt + m) * XP + quad * 8;
            short8 ah0 = *(const short8*)(sXh + base);
            short8 ah1 = *(const short8*)(sXh + base + 32);
            short8 al0 = *(const short8*)(sXl + base);
            short8 al1 = *(const short8*)(sXl + base + 32);
            int cp0 = 0, cp1 = 0;
            const int* m2 = usu_2 + (b * 8 + 2 * wt) * 8;
#pragma unroll
            for (int u = 0; u < 8; ++u) { cp0 += (m2[u] != 0); cp1 += (m2[u + 8] != 0); }
            float wg0 = cp0 > 0 ? 1.f / ((float)cp0 + 1e-8f) : 0.f;
            float wg1 = cp1 > 0 ? 1.f / ((float)cp1 + 1e-8f) : 0.f;
#pragma unroll
            for (int jj = 0; jj < 2; ++jj) {
                int J = J0 + jj;
                const int wb = (16 * J + m) * XP + quad * 8;
                short8 bh0 = *(const short8*)(sW3h + wb);
                short8 bh1 = *(const short8*)(sW3h + wb + 32);
                short8 bl0 = *(const short8*)(sW3l + wb);
                short8 bl1 = *(const short8*)(sW3l + wb + 32);
                f32x4 acc = {0.f, 0.f, 0.f, 0.f};
                acc = __builtin_amdgcn_mfma_f32_16x16x32_bf16(ah0, bh0, acc, 0, 0, 0);
                acc = __builtin_amdgcn_mfma_f32_16x16x32_bf16(ah1, bh1, acc, 0, 0, 0);
                acc = __builtin_amdgcn_mfma_f32_16x16x32_bf16(ah0, bl0, acc, 0, 0, 0);
                acc = __builtin_amdgcn_mfma_f32_16x16x32_bf16(ah1, bl1, acc, 0, 0, 0);
                acc = __builtin_amdgcn_mfma_f32_16x16x32_bf16(al0, bh0, acc, 0, 0, 0);
                acc = __builtin_amdgcn_mfma_f32_16x16x32_bf16(al1, bh1, acc, 0, 0, 0);
                float t = leakyf(acc[0]) + leakyf(acc[1]) + leakyf(acc[2]) + leakyf(acc[3]);
                t += __shfl_xor(t, 16, 64);
                if (quad == 0) sA2[(2 * wt + 0) * 64 + J * 16 + m] = t * wg0;
                if (quad == 2) sA2[(2 * wt + 1) * 64 + J * 16 + m] = t * wg1;
            }
        }
        __syncthreads();

        // Phase 3: re-stage W1u over X region (X dead); stage-2, 1 p per wave.
        stage_w512((float*)sXh, W1u, tid);
        {
            int p = w;
            float x = sA2[p * 64 + lane];
            float u1e = E_s[(size_t)usu_1[b * 8 + p] * 64 + lane];
            float y = leakyf(dot2_lds(x + u1e, x * u1e, sW21, sW22, lane));
            sA2[p * 64 + lane] = y;          // overlay: own row only
        }
        __syncthreads();

        if (w == 0) {
            float sE = 0.f; int cnt = 0;
            const int* u1i = usu_1 + b * 8;
#pragma unroll
            for (int h = 0; h < 8; ++h) {
                sE += sA2[h * 64 + lane];
                cnt += (u1i[h] != 0);
            }
            float wgt = cnt > 0 ? 1.f / ((float)cnt + 1e-8f) : 0.f;
            float eu = leakyf(dot1_lds(sE * wgt, (float*)sXh, lane));
            emb_user[(size_t)b * 64 + lane] = eu;
        }
    } else {
        // ================= dsd branch: 4 b per block, 8 waves, fp32 ======
        const int b0 = (blockIdx.x - 1024) * 4;
        float* sW1 = (float*)smraw;      // W21, later W11
        float* sW2 = sW1 + 4096;         // W22, later W12
        float* sS1 = sW2 + 4096;         // 32 x 64 emb_s1 rows

        stage_w512(sW1, W21, tid);
        stage_w512(sW2, W22, tid);
        __syncthreads();

        // gather + stage-1: wave w owns local rows 4w..4w+3 (row = (b,h1)).
#pragma unroll
        for (int i = 0; i < 4; ++i) {
            int rl = w * 4 + i;
            int row = b0 * 8 + rl;
            int is = dsd_1[row];
            float es = E_s[(size_t)is * 64 + lane];
            const int* d2 = dsd_2 + row * 8;
            float sA = 0.f; int cnt = 0;
#pragma unroll
            for (int h = 0; h < 8; ++h) {
                int id = d2[h];
                cnt += (id != 0);
                sA += E_d[(size_t)id * 64 + lane];   // E_d[0] == 0
            }
            float wgt = cnt > 0 ? 1.f / ((float)cnt + 1e-8f) : 0.f;
            float A = sA * wgt;
            sS1[rl * 64 + lane] = leakyf(dot2_lds(A + es, A * es, sW1, sW2, lane));
        }
        __syncthreads();
        stage_w512(sW1, W11, tid);
        stage_w512(sW2, W12, tid);
        __syncthreads();

        if (w < 4) {
            int b = b0 + w;
            float sE = 0.f; int cnt = 0;
            const int* d1 = dsd_1 + b * 8;
#pragma unroll
            for (int h = 0; h < 8; ++h) {
                sE += sS1[(w * 8 + h) * 64 + lane];
                cnt += (d1[h] != 0);
            }
            float wgt = cnt > 0 ? 1.f / ((float)cnt + 1e-8f) : 0.f;
            float A3 = sE * wgt;
            float td = E_d[(size_t)label[b] * 64 + lane];
            emb_dise[(size_t)b * 64 + lane] = leakyf(dot2_lds(A3 + td, A3 * td, sW1, sW2, lane));
        }
    }
}

// ---- epilogue: out[b] = dot(emb_dise[b], emb_user[b]) ----
__global__ __launch_bounds__(256) void k_dot(const float* __restrict__ ed,
                                             const float* __restrict__ eu,
                                             float* __restrict__ out) {
    const int lane = threadIdx.x & 63;
    const int b = rfl((int)((blockIdx.x * blockDim.x + threadIdx.x) >> 6));
    float pr = ed[(size_t)b * 64 + lane] * eu[(size_t)b * 64 + lane];
#pragma unroll
    for (int off = 32; off > 0; off >>= 1) pr += __shfl_down(pr, off, 64);
    if (lane == 0) out[b] = pr;
}

extern "C" void kernel_launch(void* const* d_in, const int* in_sizes, int n_in,
                              void* d_out, int out_size, void* d_ws, size_t ws_size,
                              hipStream_t stream) {
    const float* E_s  = (const float*)d_in[0];
    const float* E_d  = (const float*)d_in[1];
    const float* W_dsd_21 = (const float*)d_in[2];
    const float* W_dsd_22 = (const float*)d_in[3];
    const float* W_dsd_11 = (const float*)d_in[4];
    const float* W_dsd_12 = (const float*)d_in[5];
    const float* W_usu_3  = (const float*)d_in[6];
    const float* W_usu_21 = (const float*)d_in[7];
    const float* W_usu_22 = (const float*)d_in[8];
    const float* W_usu_1  = (const float*)d_in[9];
    const int* label = (const int*)d_in[10];
    const int* dsd_1 = (const int*)d_in[11];
    const int* dsd_2 = (const int*)d_in[12];
    const int* usu_1 = (const int*)d_in[13];
    const int* usu_2 = (const int*)d_in[14];
    const int* usu_3 = (const int*)d_in[15];
    float* out = (float*)d_out;

    // ws: Ebf [50001*64 bf16 = 6,400,128 B] | emb_dise [256 KB] | emb_user [256 KB]
    unsigned short* Ebf = (unsigned short*)d_ws;
    float* emb_dise = (float*)((char*)d_ws + 6400128);
    float* emb_user = emb_dise + 1024 * 64;

    k_cvt<<<1563, 256, 0, stream>>>(E_s, Ebf);
    k_main<<<1280, 512, 0, stream>>>(E_s, Ebf, E_d,
                                     W_dsd_21, W_dsd_22, W_dsd_11, W_dsd_12,
                                     W_usu_3, W_usu_21, W_usu_22, W_usu_1,
                                     label, dsd_1, dsd_2, usu_1, usu_2, usu_3,
                                     emb_dise, emb_user);
    k_dot<<<256, 256, 0, stream>>>(emb_dise, emb_user, out);
}

// Round 7
// 123.886 us; speedup vs baseline: 1.5722x; 1.0164x over previous
//
#include <hip/hip_runtime.h>
#include <hip/hip_bf16.h>

// HGNN forward, MI355X.
// R7: occupancy push. R6 was capped at 16 waves/CU by BOTH VGPR(128) and
// LDS(71.7KB). Single-bf16 X and W3 (2 MFMAs, was 6 with hi/lo) cuts usu LDS
// to 53.2KB = 3 blocks/CU; __launch_bounds__(512,6) caps VGPR at 80 for
// 6 waves/SIMD. Precision anchor: R5/R6 absmax 3.05e-5 with one bf16 leaf
// rounding; two more independent same-scale sources ~ sqrt(3)-3x => ~1e-4,
// threshold 3.98e-4. dsd branch stays fp32. Harness floor (~85us of d_ws
// poison fills + restores) is untouchable; controllable = k_cvt+k_main+k_dot.

typedef __attribute__((ext_vector_type(8))) short short8;
typedef __attribute__((ext_vector_type(8))) unsigned short ushort8;
typedef __attribute__((ext_vector_type(4))) float f32x4;

__device__ __forceinline__ int rfl(int v) { return __builtin_amdgcn_readfirstlane(v); }
__device__ __forceinline__ float bcastf(float v, int l) {
    return __int_as_float(__builtin_amdgcn_readlane(__float_as_int(v), l));
}
__device__ __forceinline__ float leakyf(float x) { return x >= 0.f ? x : 0.2f * x; }

__device__ __forceinline__ unsigned short bf16bits(float x) {
    __hip_bfloat16 h = __float2bfloat16(x);
    return __builtin_bit_cast(unsigned short, h);
}
__device__ __forceinline__ float bf16tof(unsigned short s) {
    __hip_bfloat16 h = __builtin_bit_cast(__hip_bfloat16, s);
    return __bfloat162float(h);
}

// Swizzled LDS fp32 weight layout (R3-verified): element [j][k] at float4
// index 16*j + (((k>>2)+j)&15). 512-thread stager: 2 float4 per thread.
__device__ __forceinline__ void stage_w512(float* dst, const float* __restrict__ W, int tid) {
#pragma unroll
    for (int c = 0; c < 2; ++c) {
        int f4 = c * 512 + tid;
        int j = f4 >> 4, g = f4 & 15;
        float4 v = reinterpret_cast<const float4*>(W)[f4];
        reinterpret_cast<float4*>(dst)[(j << 4) + ((g + j) & 15)] = v;
    }
}

__device__ __forceinline__ float dot1_lds(float x, const float* w, int lane) {
    float a0 = 0.f, a1 = 0.f, a2 = 0.f, a3 = 0.f;
#pragma unroll
    for (int g = 0; g < 16; ++g) {
        float4 c = reinterpret_cast<const float4*>(w)[(lane << 4) + ((g + lane) & 15)];
        int k = 4 * g;
        a0 = fmaf(bcastf(x, k + 0), c.x, a0);
        a1 = fmaf(bcastf(x, k + 1), c.y, a1);
        a2 = fmaf(bcastf(x, k + 2), c.z, a2);
        a3 = fmaf(bcastf(x, k + 3), c.w, a3);
    }
    return (a0 + a1) + (a2 + a3);
}

__device__ __forceinline__ float dot2_lds(float xs, float xm,
                                          const float* w1, const float* w2, int lane) {
    float a0 = 0.f, a1 = 0.f, a2 = 0.f, a3 = 0.f;
#pragma unroll
    for (int g = 0; g < 16; ++g) {
        int f4 = (lane << 4) + ((g + lane) & 15);
        float4 c1 = reinterpret_cast<const float4*>(w1)[f4];
        float4 c2 = reinterpret_cast<const float4*>(w2)[f4];
        int k = 4 * g;
        float s0 = bcastf(xs, k + 0), s1 = bcastf(xs, k + 1);
        float s2 = bcastf(xs, k + 2), s3 = bcastf(xs, k + 3);
        float m0 = bcastf(xm, k + 0), m1 = bcastf(xm, k + 1);
        float m2 = bcastf(xm, k + 2), m3 = bcastf(xm, k + 3);
        a0 = fmaf(s0, c1.x, a0); a1 = fmaf(m0, c2.x, a1);
        a2 = fmaf(s1, c1.y, a2); a3 = fmaf(m1, c2.y, a3);
        a0 = fmaf(s2, c1.z, a0); a1 = fmaf(m2, c2.z, a1);
        a2 = fmaf(s3, c1.w, a2); a3 = fmaf(m3, c2.w, a3);
    }
    return (a0 + a1) + (a2 + a3);
}

// ---- E_s fp32 -> bf16 table ----
__global__ __launch_bounds__(256) void k_cvt(const float* __restrict__ E_s,
                                             unsigned short* __restrict__ T) {
    int t = blockIdx.x * 256 + threadIdx.x;
    if (t >= 400008) return;
    const float4* p = reinterpret_cast<const float4*>(E_s) + (size_t)t * 2;
    float4 a = p[0], b = p[1];
    ushort8 o;
    o[0] = bf16bits(a.x); o[1] = bf16bits(a.y); o[2] = bf16bits(a.z); o[3] = bf16bits(a.w);
    o[4] = bf16bits(b.x); o[5] = bf16bits(b.y); o[6] = bf16bits(b.z); o[7] = bf16bits(b.w);
    *(reinterpret_cast<ushort8*>(T) + t) = o;
}

#define XP 72   // X/W3 row pitch in shorts (144 B: 16B-aligned)

// LDS map (usu): sXb[64*72] sW3b[64*72] (ushort) | sW21[4096] sW22[4096]
//                sA2[512] (float)  => 53248 B -> 3 blocks/CU.
// LDS map (dsd): sW1[4096] sW2[4096] sS1[32*64] (float) => 40960 B.
__global__ __launch_bounds__(512, 6) void k_main(
    const float* __restrict__ E_s, const unsigned short* __restrict__ Ebf,
    const float* __restrict__ E_d,
    const float* __restrict__ W21, const float* __restrict__ W22,
    const float* __restrict__ W11, const float* __restrict__ W12,
    const float* __restrict__ W3, const float* __restrict__ W21u,
    const float* __restrict__ W22u, const float* __restrict__ W1u,
    const int* __restrict__ label, const int* __restrict__ dsd_1,
    const int* __restrict__ dsd_2, const int* __restrict__ usu_1,
    const int* __restrict__ usu_2, const int* __restrict__ usu_3,
    float* __restrict__ emb_dise, float* __restrict__ emb_user)
{
    __shared__ float4 smraw[3328];   // 53248 B
    const int tid = threadIdx.x, lane = tid & 63, w = rfl(tid >> 6);

    if (blockIdx.x < 1024) {
        // ================= usu branch: one block per b, 8 waves =========
        const int b = blockIdx.x;
        unsigned short* sXb  = (unsigned short*)smraw;       // 64 x 72 bf16
        unsigned short* sW3b = sXb + 64 * XP;                // 64 x 72 bf16
        float* sW21 = (float*)(sW3b + 64 * XP);
        float* sW22 = sW21 + 4096;
        float* sA2  = sW22 + 4096;                           // 8 x 64, reused as sES1

        // Phase 0: W3 -> bf16 (8 elems/thread); W21u/W22u fp32 swizzled.
        {
            int row = tid >> 3, c0 = (tid & 7) << 3;
            const float* src = W3 + row * 64 + c0;
#pragma unroll
            for (int i = 0; i < 8; ++i)
                sW3b[row * XP + c0 + i] = bf16bits(src[i]);
        }
        stage_w512(sW21, W21u, tid);
        stage_w512(sW22, W22u, tid);

        // Phase 1: gather + masked-avg; wave w owns rows 8w..8w+7.
        for (int i = 0; i < 8; ++i) {
            int ql = w * 8 + i;
            const int* i3 = usu_3 + ((size_t)(b * 64 + ql)) * 16;
            float s0 = 0.f, s1 = 0.f; int cnt = 0;
#pragma unroll
            for (int t = 0; t < 16; t += 2) {
                int id0 = i3[t], id1 = i3[t + 1];
                cnt += (id0 != 0) + (id1 != 0);
                s0 += bf16tof(Ebf[(size_t)id0 * 64 + lane]);   // Ebf row 0 == 0
                s1 += bf16tof(Ebf[(size_t)id1 * 64 + lane]);
            }
            float wgt = cnt > 0 ? 1.f / ((float)cnt + 1e-8f) : 0.f;
            sXb[ql * XP + lane] = bf16bits((s0 + s1) * wgt);
        }
        __syncthreads();

        // Phase 2: Y = leaky(X @ W3^T) via MFMA, wave-parallel:
        // wave w -> row-tile wt = w>>1, J in {2*(w&1), 2*(w&1)+1}.
        {
            const int m = lane & 15, quad = lane >> 4;
            const int wt = w >> 1, J0 = (w & 1) * 2;
            const int base = (16 * wt + m) * XP + quad * 8;
            short8 a0 = *(const short8*)(sXb + base);
            short8 a1 = *(const short8*)(sXb + base + 32);
            int cp0 = 0, cp1 = 0;
            const int* m2 = usu_2 + (b * 8 + 2 * wt) * 8;
#pragma unroll
            for (int u = 0; u < 8; ++u) { cp0 += (m2[u] != 0); cp1 += (m2[u + 8] != 0); }
            float wg0 = cp0 > 0 ? 1.f / ((float)cp0 + 1e-8f) : 0.f;
            float wg1 = cp1 > 0 ? 1.f / ((float)cp1 + 1e-8f) : 0.f;
#pragma unroll
            for (int jj = 0; jj < 2; ++jj) {
                int J = J0 + jj;
                const int wb = (16 * J + m) * XP + quad * 8;
                short8 b0 = *(const short8*)(sW3b + wb);
                short8 b1 = *(const short8*)(sW3b + wb + 32);
                f32x4 acc = {0.f, 0.f, 0.f, 0.f};
                acc = __builtin_amdgcn_mfma_f32_16x16x32_bf16(a0, b0, acc, 0, 0, 0);
                acc = __builtin_amdgcn_mfma_f32_16x16x32_bf16(a1, b1, acc, 0, 0, 0);
                float t = leakyf(acc[0]) + leakyf(acc[1]) + leakyf(acc[2]) + leakyf(acc[3]);
                t += __shfl_xor(t, 16, 64);
                if (quad == 0) sA2[(2 * wt + 0) * 64 + J * 16 + m] = t * wg0;
                if (quad == 2) sA2[(2 * wt + 1) * 64 + J * 16 + m] = t * wg1;
            }
        }
        __syncthreads();

        // Phase 3: re-stage W1u over X/W3 region (18432B free >= 16384B);
        // stage-2, 1 p per wave.
        stage_w512((float*)sXb, W1u, tid);
        {
            int p = w;
            float x = sA2[p * 64 + lane];
            float u1e = E_s[(size_t)usu_1[b * 8 + p] * 64 + lane];
            float y = leakyf(dot2_lds(x + u1e, x * u1e, sW21, sW22, lane));
            sA2[p * 64 + lane] = y;          // overlay: own row only
        }
        __syncthreads();

        if (w == 0) {
            float sE = 0.f; int cnt = 0;
            const int* u1i = usu_1 + b * 8;
#pragma unroll
            for (int h = 0; h < 8; ++h) {
                sE += sA2[h * 64 + lane];
                cnt += (u1i[h] != 0);
            }
            float wgt = cnt > 0 ? 1.f / ((float)cnt + 1e-8f) : 0.f;
            float eu = leakyf(dot1_lds(sE * wgt, (float*)sXb, lane));
            emb_user[(size_t)b * 64 + lane] = eu;
        }
    } else {
        // ================= dsd branch: 4 b per block, 8 waves, fp32 ======
        const int b0 = (blockIdx.x - 1024) * 4;
        float* sW1 = (float*)smraw;      // W21, later W11
        float* sW2 = sW1 + 4096;         // W22, later W12
        float* sS1 = sW2 + 4096;         // 32 x 64 emb_s1 rows

        stage_w512(sW1, W21, tid);
        stage_w512(sW2, W22, tid);
        __syncthreads();

        // gather + stage-1: wave w owns local rows 4w..4w+3 (row = (b,h1)).
#pragma unroll
        for (int i = 0; i < 4; ++i) {
            int rl = w * 4 + i;
            int row = b0 * 8 + rl;
            int is = dsd_1[row];
            float es = E_s[(size_t)is * 64 + lane];
            const int* d2 = dsd_2 + row * 8;
            float sA = 0.f; int cnt = 0;
#pragma unroll
            for (int h = 0; h < 8; ++h) {
                int id = d2[h];
                cnt += (id != 0);
                sA += E_d[(size_t)id * 64 + lane];   // E_d[0] == 0
            }
            float wgt = cnt > 0 ? 1.f / ((float)cnt + 1e-8f) : 0.f;
            float A = sA * wgt;
            sS1[rl * 64 + lane] = leakyf(dot2_lds(A + es, A * es, sW1, sW2, lane));
        }
        __syncthreads();
        stage_w512(sW1, W11, tid);
        stage_w512(sW2, W12, tid);
        __syncthreads();

        if (w < 4) {
            int b = b0 + w;
            float sE = 0.f; int cnt = 0;
            const int* d1 = dsd_1 + b * 8;
#pragma unroll
            for (int h = 0; h < 8; ++h) {
                sE += sS1[(w * 8 + h) * 64 + lane];
                cnt += (d1[h] != 0);
            }
            float wgt = cnt > 0 ? 1.f / ((float)cnt + 1e-8f) : 0.f;
            float A3 = sE * wgt;
            float td = E_d[(size_t)label[b] * 64 + lane];
            emb_dise[(size_t)b * 64 + lane] = leakyf(dot2_lds(A3 + td, A3 * td, sW1, sW2, lane));
        }
    }
}

// ---- epilogue: out[b] = dot(emb_dise[b], emb_user[b]) ----
__global__ __launch_bounds__(256) void k_dot(const float* __restrict__ ed,
                                             const float* __restrict__ eu,
                                             float* __restrict__ out) {
    const int lane = threadIdx.x & 63;
    const int b = rfl((int)((blockIdx.x * blockDim.x + threadIdx.x) >> 6));
    float pr = ed[(size_t)b * 64 + lane] * eu[(size_t)b * 64 + lane];
#pragma unroll
    for (int off = 32; off > 0; off >>= 1) pr += __shfl_down(pr, off, 64);
    if (lane == 0) out[b] = pr;
}

extern "C" void kernel_launch(void* const* d_in, const int* in_sizes, int n_in,
                              void* d_out, int out_size, void* d_ws, size_t ws_size,
                              hipStream_t stream) {
    const float* E_s  = (const float*)d_in[0];
    const float* E_d  = (const float*)d_in[1];
    const float* W_dsd_21 = (const float*)d_in[2];
    const float* W_dsd_22 = (const float*)d_in[3];
    const float* W_dsd_11 = (const float*)d_in[4];
    const float* W_dsd_12 = (const float*)d_in[5];
    const float* W_usu_3  = (const float*)d_in[6];
    const float* W_usu_21 = (const float*)d_in[7];
    const float* W_usu_22 = (const float*)d_in[8];
    const float* W_usu_1  = (const float*)d_in[9];
    const int* label = (const int*)d_in[10];
    const int* dsd_1 = (const int*)d_in[11];
    const int* dsd_2 = (const int*)d_in[12];
    const int* usu_1 = (const int*)d_in[13];
    const int* usu_2 = (const int*)d_in[14];
    const int* usu_3 = (const int*)d_in[15];
    float* out = (float*)d_out;

    // ws: Ebf [50001*64 bf16 = 6,400,128 B] | emb_dise [256 KB] | emb_user [256 KB]
    unsigned short* Ebf = (unsigned short*)d_ws;
    float* emb_dise = (float*)((char*)d_ws + 6400128);
    float* emb_user = emb_dise + 1024 * 64;

    k_cvt<<<1563, 256, 0, stream>>>(E_s, Ebf);
    k_main<<<1280, 512, 0, stream>>>(E_s, Ebf, E_d,
                                     W_dsd_21, W_dsd_22, W_dsd_11, W_dsd_12,
                                     W_usu_3, W_usu_21, W_usu_22, W_usu_1,
                                     label, dsd_1, dsd_2, usu_1, usu_2, usu_3,
                                     emb_dise, emb_user);
    k_dot<<<256, 256, 0, stream>>>(emb_dise, emb_user, out);
}

// Round 8
// 122.939 us; speedup vs baseline: 1.5843x; 1.0077x over previous
//
#include <hip/hip_runtime.h>
#include <hip/hip_bf16.h>

// HGNN forward, MI355X.
// R8: transposed phase-1 gather. R7's k_main (~39us inferred) was dominated
// by usu phase-1: 16 vmem gathers + 16 redundant idx loads + ~160 VALU per
// (p,u2) group. Now: lane=(sub*16+cg) loads uint2 (4 bf16 cols of row
// id[4k+sub]) -> 4 gather instrs per 16-id group; idx via one 64B load +
// shfl; cnt via ballot; cross-lane reduce over sub (shfl_xor 16/32).
// Everything else identical to R7 (absmax 6.1e-5, 6.5x margin).

typedef __attribute__((ext_vector_type(8))) short short8;
typedef __attribute__((ext_vector_type(8))) unsigned short ushort8;
typedef __attribute__((ext_vector_type(4))) float f32x4;

__device__ __forceinline__ int rfl(int v) { return __builtin_amdgcn_readfirstlane(v); }
__device__ __forceinline__ float bcastf(float v, int l) {
    return __int_as_float(__builtin_amdgcn_readlane(__float_as_int(v), l));
}
__device__ __forceinline__ float leakyf(float x) { return x >= 0.f ? x : 0.2f * x; }

__device__ __forceinline__ unsigned short bf16bits(float x) {
    __hip_bfloat16 h = __float2bfloat16(x);
    return __builtin_bit_cast(unsigned short, h);
}
__device__ __forceinline__ float bf16tof(unsigned short s) {
    __hip_bfloat16 h = __builtin_bit_cast(__hip_bfloat16, s);
    return __bfloat162float(h);
}
__device__ __forceinline__ float bflo(unsigned int u) {
    return __uint_as_float(u << 16);
}
__device__ __forceinline__ float bfhi(unsigned int u) {
    return __uint_as_float(u & 0xffff0000u);
}

// Swizzled LDS fp32 weight layout (R3-verified): element [j][k] at float4
// index 16*j + (((k>>2)+j)&15). 512-thread stager: 2 float4 per thread.
__device__ __forceinline__ void stage_w512(float* dst, const float* __restrict__ W, int tid) {
#pragma unroll
    for (int c = 0; c < 2; ++c) {
        int f4 = c * 512 + tid;
        int j = f4 >> 4, g = f4 & 15;
        float4 v = reinterpret_cast<const float4*>(W)[f4];
        reinterpret_cast<float4*>(dst)[(j << 4) + ((g + j) & 15)] = v;
    }
}

__device__ __forceinline__ float dot1_lds(float x, const float* w, int lane) {
    float a0 = 0.f, a1 = 0.f, a2 = 0.f, a3 = 0.f;
#pragma unroll
    for (int g = 0; g < 16; ++g) {
        float4 c = reinterpret_cast<const float4*>(w)[(lane << 4) + ((g + lane) & 15)];
        int k = 4 * g;
        a0 = fmaf(bcastf(x, k + 0), c.x, a0);
        a1 = fmaf(bcastf(x, k + 1), c.y, a1);
        a2 = fmaf(bcastf(x, k + 2), c.z, a2);
        a3 = fmaf(bcastf(x, k + 3), c.w, a3);
    }
    return (a0 + a1) + (a2 + a3);
}

__device__ __forceinline__ float dot2_lds(float xs, float xm,
                                          const float* w1, const float* w2, int lane) {
    float a0 = 0.f, a1 = 0.f, a2 = 0.f, a3 = 0.f;
#pragma unroll
    for (int g = 0; g < 16; ++g) {
        int f4 = (lane << 4) + ((g + lane) & 15);
        float4 c1 = reinterpret_cast<const float4*>(w1)[f4];
        float4 c2 = reinterpret_cast<const float4*>(w2)[f4];
        int k = 4 * g;
        float s0 = bcastf(xs, k + 0), s1 = bcastf(xs, k + 1);
        float s2 = bcastf(xs, k + 2), s3 = bcastf(xs, k + 3);
        float m0 = bcastf(xm, k + 0), m1 = bcastf(xm, k + 1);
        float m2 = bcastf(xm, k + 2), m3 = bcastf(xm, k + 3);
        a0 = fmaf(s0, c1.x, a0); a1 = fmaf(m0, c2.x, a1);
        a2 = fmaf(s1, c1.y, a2); a3 = fmaf(m1, c2.y, a3);
        a0 = fmaf(s2, c1.z, a0); a1 = fmaf(m2, c2.z, a1);
        a2 = fmaf(s3, c1.w, a2); a3 = fmaf(m3, c2.w, a3);
    }
    return (a0 + a1) + (a2 + a3);
}

// ---- E_s fp32 -> bf16 table ----
__global__ __launch_bounds__(256) void k_cvt(const float* __restrict__ E_s,
                                             unsigned short* __restrict__ T) {
    int t = blockIdx.x * 256 + threadIdx.x;
    if (t >= 400008) return;
    const float4* p = reinterpret_cast<const float4*>(E_s) + (size_t)t * 2;
    float4 a = p[0], b = p[1];
    ushort8 o;
    o[0] = bf16bits(a.x); o[1] = bf16bits(a.y); o[2] = bf16bits(a.z); o[3] = bf16bits(a.w);
    o[4] = bf16bits(b.x); o[5] = bf16bits(b.y); o[6] = bf16bits(b.z); o[7] = bf16bits(b.w);
    *(reinterpret_cast<ushort8*>(T) + t) = o;
}

#define XP 72   // X/W3 row pitch in shorts (144 B: 16B-aligned)

// LDS map (usu): sXb[64*72] sW3b[64*72] (ushort) | sW21[4096] sW22[4096]
//                sA2[512] (float)  => 53248 B -> 3 blocks/CU.
// LDS map (dsd): sW1[4096] sW2[4096] sS1[32*64] (float) => 40960 B.
__global__ __launch_bounds__(512, 6) void k_main(
    const float* __restrict__ E_s, const unsigned short* __restrict__ Ebf,
    const float* __restrict__ E_d,
    const float* __restrict__ W21, const float* __restrict__ W22,
    const float* __restrict__ W11, const float* __restrict__ W12,
    const float* __restrict__ W3, const float* __restrict__ W21u,
    const float* __restrict__ W22u, const float* __restrict__ W1u,
    const int* __restrict__ label, const int* __restrict__ dsd_1,
    const int* __restrict__ dsd_2, const int* __restrict__ usu_1,
    const int* __restrict__ usu_2, const int* __restrict__ usu_3,
    float* __restrict__ emb_dise, float* __restrict__ emb_user)
{
    __shared__ float4 smraw[3328];   // 53248 B
    const int tid = threadIdx.x, lane = tid & 63, w = rfl(tid >> 6);

    if (blockIdx.x < 1024) {
        // ================= usu branch: one block per b, 8 waves =========
        const int b = blockIdx.x;
        unsigned short* sXb  = (unsigned short*)smraw;       // 64 x 72 bf16
        unsigned short* sW3b = sXb + 64 * XP;                // 64 x 72 bf16
        float* sW21 = (float*)(sW3b + 64 * XP);
        float* sW22 = sW21 + 4096;
        float* sA2  = sW22 + 4096;                           // 8 x 64, reused as sES1

        const int sub = lane >> 4;       // 0..3: id-slot within a 4-id batch
        const int cg  = lane & 15;       // column group: cols 4cg..4cg+3

        // Hoist all 8 rows' indices: one coalesced 64B load per row.
        int idv[8];
#pragma unroll
        for (int i = 0; i < 8; ++i)
            idv[i] = usu_3[((size_t)(b * 64 + w * 8 + i)) * 16 + cg];

        // Phase 0: W3 -> bf16 (8 elems/thread); W21u/W22u fp32 swizzled.
        {
            int row = tid >> 3, c0 = (tid & 7) << 3;
            const float* src = W3 + row * 64 + c0;
#pragma unroll
            for (int i = 0; i < 8; ++i)
                sW3b[row * XP + c0 + i] = bf16bits(src[i]);
        }
        stage_w512(sW21, W21u, tid);
        stage_w512(sW22, W22u, tid);

        // Phase 1: transposed gather + masked-avg; wave w owns rows 8w..8w+7.
        // One uint2 load = 4 bf16 cols of row id[4k+sub]; 4 loads per 16-id row.
#pragma unroll 2
        for (int i = 0; i < 8; ++i) {
            int ql = w * 8 + i;
            unsigned long long nzm = __ballot(idv[i] != 0) & 0xFFFFull;
            int cnt = (int)__popcll(nzm);
            float wgt = cnt > 0 ? 1.f / ((float)cnt + 1e-8f) : 0.f;
            float a0 = 0.f, a1 = 0.f, a2 = 0.f, a3 = 0.f;
#pragma unroll
            for (int k = 0; k < 4; ++k) {
                int id = __shfl(idv[i], k * 4 + sub, 64);
                uint2 v = *reinterpret_cast<const uint2*>(Ebf + (size_t)id * 64 + cg * 4);
                a0 += bflo(v.x); a1 += bfhi(v.x);    // Ebf row 0 == 0
                a2 += bflo(v.y); a3 += bfhi(v.y);
            }
            // reduce over sub (lanes xor 16, 32)
            a0 += __shfl_xor(a0, 16, 64); a1 += __shfl_xor(a1, 16, 64);
            a2 += __shfl_xor(a2, 16, 64); a3 += __shfl_xor(a3, 16, 64);
            a0 += __shfl_xor(a0, 32, 64); a1 += __shfl_xor(a1, 32, 64);
            a2 += __shfl_xor(a2, 32, 64); a3 += __shfl_xor(a3, 32, 64);
            a0 *= wgt; a1 *= wgt; a2 *= wgt; a3 *= wgt;
            unsigned int p0 = ((unsigned int)bf16bits(a1) << 16) | bf16bits(a0);
            unsigned int p1 = ((unsigned int)bf16bits(a3) << 16) | bf16bits(a2);
            if (sub == 0) {
                uint2 st; st.x = p0; st.y = p1;
                *reinterpret_cast<uint2*>(sXb + ql * XP + cg * 4) = st;
            }
        }
        __syncthreads();

        // Phase 2: Y = leaky(X @ W3^T) via MFMA, wave-parallel:
        // wave w -> row-tile wt = w>>1, J in {2*(w&1), 2*(w&1)+1}.
        {
            const int m = lane & 15, quad = lane >> 4;
            const int wt = w >> 1, J0 = (w & 1) * 2;
            const int base = (16 * wt + m) * XP + quad * 8;
            short8 a0 = *(const short8*)(sXb + base);
            short8 a1 = *(const short8*)(sXb + base + 32);
            int cp0 = 0, cp1 = 0;
            const int* m2 = usu_2 + (b * 8 + 2 * wt) * 8;
#pragma unroll
            for (int u = 0; u < 8; ++u) { cp0 += (m2[u] != 0); cp1 += (m2[u + 8] != 0); }
            float wg0 = cp0 > 0 ? 1.f / ((float)cp0 + 1e-8f) : 0.f;
            float wg1 = cp1 > 0 ? 1.f / ((float)cp1 + 1e-8f) : 0.f;
#pragma unroll
            for (int jj = 0; jj < 2; ++jj) {
                int J = J0 + jj;
                const int wb = (16 * J + m) * XP + quad * 8;
                short8 b0 = *(const short8*)(sW3b + wb);
                short8 b1 = *(const short8*)(sW3b + wb + 32);
                f32x4 acc = {0.f, 0.f, 0.f, 0.f};
                acc = __builtin_amdgcn_mfma_f32_16x16x32_bf16(a0, b0, acc, 0, 0, 0);
                acc = __builtin_amdgcn_mfma_f32_16x16x32_bf16(a1, b1, acc, 0, 0, 0);
                float t = leakyf(acc[0]) + leakyf(acc[1]) + leakyf(acc[2]) + leakyf(acc[3]);
                t += __shfl_xor(t, 16, 64);
                if (quad == 0) sA2[(2 * wt + 0) * 64 + J * 16 + m] = t * wg0;
                if (quad == 2) sA2[(2 * wt + 1) * 64 + J * 16 + m] = t * wg1;
            }
        }
        __syncthreads();

        // Phase 3: re-stage W1u over X/W3 region (X dead); stage-2, 1 p per wave.
        stage_w512((float*)sXb, W1u, tid);
        {
            int p = w;
            float x = sA2[p * 64 + lane];
            float u1e = E_s[(size_t)usu_1[b * 8 + p] * 64 + lane];
            float y = leakyf(dot2_lds(x + u1e, x * u1e, sW21, sW22, lane));
            sA2[p * 64 + lane] = y;          // overlay: own row only
        }
        __syncthreads();

        if (w == 0) {
            float sE = 0.f; int cnt = 0;
            const int* u1i = usu_1 + b * 8;
#pragma unroll
            for (int h = 0; h < 8; ++h) {
                sE += sA2[h * 64 + lane];
                cnt += (u1i[h] != 0);
            }
            float wgt = cnt > 0 ? 1.f / ((float)cnt + 1e-8f) : 0.f;
            float eu = leakyf(dot1_lds(sE * wgt, (float*)sXb, lane));
            emb_user[(size_t)b * 64 + lane] = eu;
        }
    } else {
        // ================= dsd branch: 4 b per block, 8 waves, fp32 ======
        const int b0 = (blockIdx.x - 1024) * 4;
        float* sW1 = (float*)smraw;      // W21, later W11
        float* sW2 = sW1 + 4096;         // W22, later W12
        float* sS1 = sW2 + 4096;         // 32 x 64 emb_s1 rows

        stage_w512(sW1, W21, tid);
        stage_w512(sW2, W22, tid);
        __syncthreads();

        // gather + stage-1: wave w owns local rows 4w..4w+3 (row = (b,h1)).
#pragma unroll
        for (int i = 0; i < 4; ++i) {
            int rl = w * 4 + i;
            int row = b0 * 8 + rl;
            int is = dsd_1[row];
            float es = E_s[(size_t)is * 64 + lane];
            const int* d2 = dsd_2 + row * 8;
            float sA = 0.f; int cnt = 0;
#pragma unroll
            for (int h = 0; h < 8; ++h) {
                int id = d2[h];
                cnt += (id != 0);
                sA += E_d[(size_t)id * 64 + lane];   // E_d[0] == 0
            }
            float wgt = cnt > 0 ? 1.f / ((float)cnt + 1e-8f) : 0.f;
            float A = sA * wgt;
            sS1[rl * 64 + lane] = leakyf(dot2_lds(A + es, A * es, sW1, sW2, lane));
        }
        __syncthreads();
        stage_w512(sW1, W11, tid);
        stage_w512(sW2, W12, tid);
        __syncthreads();

        if (w < 4) {
            int b = b0 + w;
            float sE = 0.f; int cnt = 0;
            const int* d1 = dsd_1 + b * 8;
#pragma unroll
            for (int h = 0; h < 8; ++h) {
                sE += sS1[(w * 8 + h) * 64 + lane];
                cnt += (d1[h] != 0);
            }
            float wgt = cnt > 0 ? 1.f / ((float)cnt + 1e-8f) : 0.f;
            float A3 = sE * wgt;
            float td = E_d[(size_t)label[b] * 64 + lane];
            emb_dise[(size_t)b * 64 + lane] = leakyf(dot2_lds(A3 + td, A3 * td, sW1, sW2, lane));
        }
    }
}

// ---- epilogue: out[b] = dot(emb_dise[b], emb_user[b]) ----
__global__ __launch_bounds__(256) void k_dot(const float* __restrict__ ed,
                                             const float* __restrict__ eu,
                                             float* __restrict__ out) {
    const int lane = threadIdx.x & 63;
    const int b = rfl((int)((blockIdx.x * blockDim.x + threadIdx.x) >> 6));
    float pr = ed[(size_t)b * 64 + lane] * eu[(size_t)b * 64 + lane];
#pragma unroll
    for (int off = 32; off > 0; off >>= 1) pr += __shfl_down(pr, off, 64);
    if (lane == 0) out[b] = pr;
}

extern "C" void kernel_launch(void* const* d_in, const int* in_sizes, int n_in,
                              void* d_out, int out_size, void* d_ws, size_t ws_size,
                              hipStream_t stream) {
    const float* E_s  = (const float*)d_in[0];
    const float* E_d  = (const float*)d_in[1];
    const float* W_dsd_21 = (const float*)d_in[2];
    const float* W_dsd_22 = (const float*)d_in[3];
    const float* W_dsd_11 = (const float*)d_in[4];
    const float* W_dsd_12 = (const float*)d_in[5];
    const float* W_usu_3  = (const float*)d_in[6];
    const float* W_usu_21 = (const float*)d_in[7];
    const float* W_usu_22 = (const float*)d_in[8];
    const float* W_usu_1  = (const float*)d_in[9];
    const int* label = (const int*)d_in[10];
    const int* dsd_1 = (const int*)d_in[11];
    const int* dsd_2 = (const int*)d_in[12];
    const int* usu_1 = (const int*)d_in[13];
    const int* usu_2 = (const int*)d_in[14];
    const int* usu_3 = (const int*)d_in[15];
    float* out = (float*)d_out;

    // ws: Ebf [50001*64 bf16 = 6,400,128 B] | emb_dise [256 KB] | emb_user [256 KB]
    unsigned short* Ebf = (unsigned short*)d_ws;
    float* emb_dise = (float*)((char*)d_ws + 6400128);
    float* emb_user = emb_dise + 1024 * 64;

    k_cvt<<<1563, 256, 0, stream>>>(E_s, Ebf);
    k_main<<<1280, 512, 0, stream>>>(E_s, Ebf, E_d,
                                     W_dsd_21, W_dsd_22, W_dsd_11, W_dsd_12,
                                     W_usu_3, W_usu_21, W_usu_22, W_usu_1,
                                     label, dsd_1, dsd_2, usu_1, usu_2, usu_3,
                                     emb_dise, emb_user);
    k_dot<<<256, 256, 0, stream>>>(emb_dise, emb_user, out);
}

// Round 9
// 116.092 us; speedup vs baseline: 1.6777x; 1.0590x over previous
//
#include <hip/hip_runtime.h>
#include <hip/hip_bf16.h>

// HGNN forward, MI355X.
// R9: MFMA everywhere. usu stage-2, dsd stage-1, dsd stage-2 converted from
// readlane-dot (300+ VALU instr per row-wave) to 16x16x32 bf16 MFMA via the
// K-concat identity xs@W1^T + xm@W2^T = [xs|xm] @ [W1|W2]^T (4 MFMAs per
// 16x16 tile). Layouts per R4/R8-verified mappings. LDS 53.2->40KB.
// Phase-1 transposed gather (R8), bf16 E_s table (R5), fp32 final dot kept.

typedef __attribute__((ext_vector_type(8))) short short8;
typedef __attribute__((ext_vector_type(8))) unsigned short ushort8;
typedef __attribute__((ext_vector_type(4))) float f32x4;

__device__ __forceinline__ int rfl(int v) { return __builtin_amdgcn_readfirstlane(v); }
__device__ __forceinline__ float bcastf(float v, int l) {
    return __int_as_float(__builtin_amdgcn_readlane(__float_as_int(v), l));
}
__device__ __forceinline__ float leakyf(float x) { return x >= 0.f ? x : 0.2f * x; }

__device__ __forceinline__ unsigned short bf16bits(float x) {
    __hip_bfloat16 h = __float2bfloat16(x);
    return __builtin_bit_cast(unsigned short, h);
}
__device__ __forceinline__ float bflo(unsigned int u) { return __uint_as_float(u << 16); }
__device__ __forceinline__ float bfhi(unsigned int u) { return __uint_as_float(u & 0xffff0000u); }

// Swizzled LDS fp32 weight layout (R3-verified): element [j][k] at float4
// index 16*j + (((k>>2)+j)&15). 512-thread stager: 2 float4 per thread.
__device__ __forceinline__ void stage_w512(float* dst, const float* __restrict__ W, int tid) {
#pragma unroll
    for (int c = 0; c < 2; ++c) {
        int f4 = c * 512 + tid;
        int j = f4 >> 4, g = f4 & 15;
        float4 v = reinterpret_cast<const float4*>(W)[f4];
        reinterpret_cast<float4*>(dst)[(j << 4) + ((g + j) & 15)] = v;
    }
}

__device__ __forceinline__ float dot1_lds(float x, const float* w, int lane) {
    float a0 = 0.f, a1 = 0.f, a2 = 0.f, a3 = 0.f;
#pragma unroll
    for (int g = 0; g < 16; ++g) {
        float4 c = reinterpret_cast<const float4*>(w)[(lane << 4) + ((g + lane) & 15)];
        int k = 4 * g;
        a0 = fmaf(bcastf(x, k + 0), c.x, a0);
        a1 = fmaf(bcastf(x, k + 1), c.y, a1);
        a2 = fmaf(bcastf(x, k + 2), c.z, a2);
        a3 = fmaf(bcastf(x, k + 3), c.w, a3);
    }
    return (a0 + a1) + (a2 + a3);
}

// ---- E_s fp32 -> bf16 table ----
__global__ __launch_bounds__(256) void k_cvt(const float* __restrict__ E_s,
                                             unsigned short* __restrict__ T) {
    int t = blockIdx.x * 256 + threadIdx.x;
    if (t >= 400008) return;
    const float4* p = reinterpret_cast<const float4*>(E_s) + (size_t)t * 2;
    float4 a = p[0], b = p[1];
    ushort8 o;
    o[0] = bf16bits(a.x); o[1] = bf16bits(a.y); o[2] = bf16bits(a.z); o[3] = bf16bits(a.w);
    o[4] = bf16bits(b.x); o[5] = bf16bits(b.y); o[6] = bf16bits(b.z); o[7] = bf16bits(b.w);
    *(reinterpret_cast<ushort8*>(T) + t) = o;
}

#define XP 72   // bf16 matrix row pitch in shorts (144 B: 16B-aligned)

// 4-MFMA pair-matmul accumulate: acc += As@Wb1(K32x2) + Am@Wb2(K32x2)
__device__ __forceinline__ f32x4 pair_mfma(
    const unsigned short* sXs, const unsigned short* sXm,
    const unsigned short* sWb1, const unsigned short* sWb2,
    int arow, int brow, int quad)
{
    const int ab = arow * XP + quad * 8;
    const int bb = brow * XP + quad * 8;
    short8 as0 = *(const short8*)(sXs + ab);
    short8 as1 = *(const short8*)(sXs + ab + 32);
    short8 am0 = *(const short8*)(sXm + ab);
    short8 am1 = *(const short8*)(sXm + ab + 32);
    short8 b10 = *(const short8*)(sWb1 + bb);
    short8 b11 = *(const short8*)(sWb1 + bb + 32);
    short8 b20 = *(const short8*)(sWb2 + bb);
    short8 b21 = *(const short8*)(sWb2 + bb + 32);
    f32x4 acc = {0.f, 0.f, 0.f, 0.f};
    acc = __builtin_amdgcn_mfma_f32_16x16x32_bf16(as0, b10, acc, 0, 0, 0);
    acc = __builtin_amdgcn_mfma_f32_16x16x32_bf16(as1, b11, acc, 0, 0, 0);
    acc = __builtin_amdgcn_mfma_f32_16x16x32_bf16(am0, b20, acc, 0, 0, 0);
    acc = __builtin_amdgcn_mfma_f32_16x16x32_bf16(am1, b21, acc, 0, 0, 0);
    return acc;
}

// LDS (usu): sXb[64x72] sW3b[64x72] sW21b[64x72] sW22b[64x72] (ushort)
//            sA2[512] sES1[512] (float) = 40960 B.
// LDS (dsd): sXs[32x72] sXm[32x72] sW21b[64x72] sW22b[64x72] sS1[32x64 f]
//            = 35840 B.
__global__ __launch_bounds__(512, 6) void k_main(
    const float* __restrict__ E_s, const unsigned short* __restrict__ Ebf,
    const float* __restrict__ E_d,
    const float* __restrict__ W21, const float* __restrict__ W22,
    const float* __restrict__ W11, const float* __restrict__ W12,
    const float* __restrict__ W3, const float* __restrict__ W21u,
    const float* __restrict__ W22u, const float* __restrict__ W1u,
    const int* __restrict__ label, const int* __restrict__ dsd_1,
    const int* __restrict__ dsd_2, const int* __restrict__ usu_1,
    const int* __restrict__ usu_2, const int* __restrict__ usu_3,
    float* __restrict__ emb_dise, float* __restrict__ emb_user)
{
    __shared__ float4 smraw[2560];   // 40960 B
    const int tid = threadIdx.x, lane = tid & 63, w = rfl(tid >> 6);
    const int m_ = lane & 15, quad = lane >> 4;

    if (blockIdx.x < 1024) {
        // ================= usu branch: one block per b, 8 waves =========
        const int b = blockIdx.x;
        unsigned short* sXb   = (unsigned short*)smraw;   // 64x72
        unsigned short* sW3b  = sXb + 4608;
        unsigned short* sW21b = sW3b + 4608;
        unsigned short* sW22b = sW21b + 4608;
        float* sA2  = (float*)(sW22b + 4608);             // 8x64
        float* sES1 = sA2 + 512;                          // 8x64
        unsigned short* sXs = sXb;                        // phase3: 16x72
        unsigned short* sXm = sXb + 16 * XP;

        const int sub = lane >> 4, cg = lane & 15;

        // Hoist indices: one coalesced load per row.
        int idv[8];
#pragma unroll
        for (int i = 0; i < 8; ++i)
            idv[i] = usu_3[((size_t)(b * 64 + w * 8 + i)) * 16 + cg];

        // Phase 0: W3/W21u/W22u -> bf16 LDS (8 elems/thread each).
        {
            int row = tid >> 3, c0 = (tid & 7) << 3;
            const float* p3 = W3 + row * 64 + c0;
            const float* p1 = W21u + row * 64 + c0;
            const float* p2 = W22u + row * 64 + c0;
#pragma unroll
            for (int i = 0; i < 8; ++i) {
                sW3b[row * XP + c0 + i]  = bf16bits(p3[i]);
                sW21b[row * XP + c0 + i] = bf16bits(p1[i]);
                sW22b[row * XP + c0 + i] = bf16bits(p2[i]);
            }
        }

        // Phase 1: transposed gather + masked-avg (R8-verified).
#pragma unroll 2
        for (int i = 0; i < 8; ++i) {
            int ql = w * 8 + i;
            unsigned long long nzm = __ballot(idv[i] != 0) & 0xFFFFull;
            int cnt = (int)__popcll(nzm);
            float wgt = cnt > 0 ? 1.f / ((float)cnt + 1e-8f) : 0.f;
            float a0 = 0.f, a1 = 0.f, a2 = 0.f, a3 = 0.f;
#pragma unroll
            for (int k = 0; k < 4; ++k) {
                int id = __shfl(idv[i], k * 4 + sub, 64);
                uint2 v = *reinterpret_cast<const uint2*>(Ebf + (size_t)id * 64 + cg * 4);
                a0 += bflo(v.x); a1 += bfhi(v.x);
                a2 += bflo(v.y); a3 += bfhi(v.y);
            }
            a0 += __shfl_xor(a0, 16, 64); a1 += __shfl_xor(a1, 16, 64);
            a2 += __shfl_xor(a2, 16, 64); a3 += __shfl_xor(a3, 16, 64);
            a0 += __shfl_xor(a0, 32, 64); a1 += __shfl_xor(a1, 32, 64);
            a2 += __shfl_xor(a2, 32, 64); a3 += __shfl_xor(a3, 32, 64);
            a0 *= wgt; a1 *= wgt; a2 *= wgt; a3 *= wgt;
            unsigned int p0 = ((unsigned int)bf16bits(a1) << 16) | bf16bits(a0);
            unsigned int p1 = ((unsigned int)bf16bits(a3) << 16) | bf16bits(a2);
            if (sub == 0) {
                uint2 st; st.x = p0; st.y = p1;
                *reinterpret_cast<uint2*>(sXb + ql * XP + cg * 4) = st;
            }
        }
        __syncthreads();

        // Phase 2: Y = leaky(X @ W3^T) via MFMA; u2-reduction in C-layout.
        {
            const int wt = w >> 1, J0 = (w & 1) * 2;
            const int base = (16 * wt + m_) * XP + quad * 8;
            short8 a0 = *(const short8*)(sXb + base);
            short8 a1 = *(const short8*)(sXb + base + 32);
            int cp0 = 0, cp1 = 0;
            const int* m2 = usu_2 + (b * 8 + 2 * wt) * 8;
#pragma unroll
            for (int u = 0; u < 8; ++u) { cp0 += (m2[u] != 0); cp1 += (m2[u + 8] != 0); }
            float wg0 = cp0 > 0 ? 1.f / ((float)cp0 + 1e-8f) : 0.f;
            float wg1 = cp1 > 0 ? 1.f / ((float)cp1 + 1e-8f) : 0.f;
#pragma unroll
            for (int jj = 0; jj < 2; ++jj) {
                int J = J0 + jj;
                const int wb = (16 * J + m_) * XP + quad * 8;
                short8 b0 = *(const short8*)(sW3b + wb);
                short8 b1 = *(const short8*)(sW3b + wb + 32);
                f32x4 acc = {0.f, 0.f, 0.f, 0.f};
                acc = __builtin_amdgcn_mfma_f32_16x16x32_bf16(a0, b0, acc, 0, 0, 0);
                acc = __builtin_amdgcn_mfma_f32_16x16x32_bf16(a1, b1, acc, 0, 0, 0);
                float t = leakyf(acc[0]) + leakyf(acc[1]) + leakyf(acc[2]) + leakyf(acc[3]);
                t += __shfl_xor(t, 16, 64);
                if (quad == 0) sA2[(2 * wt + 0) * 64 + J * 16 + m_] = t * wg0;
                if (quad == 2) sA2[(2 * wt + 1) * 64 + J * 16 + m_] = t * wg1;
            }
        }
        __syncthreads();

        // Phase 3a: build stage-2 A rows (wave w -> p=w): xs=x+u, xm=x*u.
        {
            int p = w;
            float x = sA2[p * 64 + lane];
            float u1e = E_s[(size_t)usu_1[b * 8 + p] * 64 + lane];
            sXs[p * XP + lane] = bf16bits(x + u1e);
            sXm[p * XP + lane] = bf16bits(x * u1e);
        }
        __syncthreads();

        // Phase 3b: stage-2 MFMA (waves 0-3, J=w): rows 0-7 valid.
        if (w < 4) {
            f32x4 acc = pair_mfma(sXs, sXm, sW21b, sW22b, m_, 16 * w + m_, quad);
            if (quad < 2) {
#pragma unroll
                for (int r = 0; r < 4; ++r)
                    sES1[(quad * 4 + r) * 64 + w * 16 + m_] = leakyf(acc[r]);
            }
        }
        __syncthreads();

        // Phase 3c: W1u fp32 swizzled over sW21b/sW22b region (dead now).
        stage_w512((float*)sW21b, W1u, tid);
        __syncthreads();

        // Phase 3d: final masked-avg + W1u transform (wave 0).
        if (w == 0) {
            float sE = 0.f; int cnt = 0;
            const int* u1i = usu_1 + b * 8;
#pragma unroll
            for (int h = 0; h < 8; ++h) {
                sE += sES1[h * 64 + lane];
                cnt += (u1i[h] != 0);
            }
            float wgt = cnt > 0 ? 1.f / ((float)cnt + 1e-8f) : 0.f;
            float eu = leakyf(dot1_lds(sE * wgt, (float*)sW21b, lane));
            emb_user[(size_t)b * 64 + lane] = eu;
        }
    } else {
        // ================= dsd branch: 4 b per block, 8 waves, MFMA ======
        const int b0 = (blockIdx.x - 1024) * 4;
        unsigned short* sXs   = (unsigned short*)smraw;   // 32x72
        unsigned short* sXm   = sXs + 2304;               // 32x72
        unsigned short* sW21b = sXm + 2304;               // 64x72 (W21 -> W11)
        unsigned short* sW22b = sW21b + 4608;             // 64x72 (W22 -> W12)
        float* sS1 = (float*)(sW22b + 4608);              // 32x64 fp32

        // Phase 0: W21/W22 -> bf16 LDS.
        {
            int row = tid >> 3, c0 = (tid & 7) << 3;
            const float* p1 = W21 + row * 64 + c0;
            const float* p2 = W22 + row * 64 + c0;
#pragma unroll
            for (int i = 0; i < 8; ++i) {
                sW21b[row * XP + c0 + i] = bf16bits(p1[i]);
                sW22b[row * XP + c0 + i] = bf16bits(p2[i]);
            }
        }

        // Phase 1: gathers + build stage-1 A rows (wave w: rows 4w..4w+3).
#pragma unroll
        for (int i = 0; i < 4; ++i) {
            int rl = w * 4 + i;
            int row = b0 * 8 + rl;
            int is = dsd_1[row];
            float es = E_s[(size_t)is * 64 + lane];
            const int* d2 = dsd_2 + row * 8;
            float sA = 0.f; int cnt = 0;
#pragma unroll
            for (int h = 0; h < 8; ++h) {
                int id = d2[h];
                cnt += (id != 0);
                sA += E_d[(size_t)id * 64 + lane];   // E_d[0] == 0
            }
            float wgt = cnt > 0 ? 1.f / ((float)cnt + 1e-8f) : 0.f;
            float A = sA * wgt;
            sXs[rl * XP + lane] = bf16bits(A + es);
            sXm[rl * XP + lane] = bf16bits(A * es);
        }
        __syncthreads();

        // Phase 2: stage-1 MFMA: wave w -> Mt=w>>2, J=w&3; all 16 rows valid.
        {
            const int Mt = w >> 2, J = w & 3;
            f32x4 acc = pair_mfma(sXs, sXm, sW21b, sW22b,
                                  16 * Mt + m_, 16 * J + m_, quad);
#pragma unroll
            for (int r = 0; r < 4; ++r)
                sS1[(16 * Mt + quad * 4 + r) * 64 + J * 16 + m_] = leakyf(acc[r]);
        }
        __syncthreads();

        // Phase 3: waves 0-3 build stage-2 A rows (p=w -> b0+w);
        //          waves 4-7 convert W11/W12 over W21/W22 slots.
        if (w < 4) {
            int bb = b0 + w;
            float sE = 0.f; int cnt = 0;
            const int* d1 = dsd_1 + bb * 8;
#pragma unroll
            for (int h = 0; h < 8; ++h) {
                sE += sS1[(w * 8 + h) * 64 + lane];
                cnt += (d1[h] != 0);
            }
            float wgt = cnt > 0 ? 1.f / ((float)cnt + 1e-8f) : 0.f;
            float A3 = sE * wgt;
            float td = E_d[(size_t)label[bb] * 64 + lane];
            sXs[w * XP + lane] = bf16bits(A3 + td);
            sXm[w * XP + lane] = bf16bits(A3 * td);
        } else {
            int t2 = tid - 256;                 // 0..255
            int row = t2 >> 2, c0 = (t2 & 3) << 4;
            const float* p1 = W11 + row * 64 + c0;
            const float* p2 = W12 + row * 64 + c0;
#pragma unroll
            for (int i = 0; i < 16; ++i) {
                sW21b[row * XP + c0 + i] = bf16bits(p1[i]);
                sW22b[row * XP + c0 + i] = bf16bits(p2[i]);
            }
        }
        __syncthreads();

        // Phase 4: stage-2 MFMA (waves 0-3, J=w): rows 0-3 valid (quad 0).
        if (w < 4) {
            f32x4 acc = pair_mfma(sXs, sXm, sW21b, sW22b, m_, 16 * w + m_, quad);
            if (quad == 0) {
#pragma unroll
                for (int r = 0; r < 4; ++r)
                    emb_dise[(size_t)(b0 + r) * 64 + w * 16 + m_] = leakyf(acc[r]);
            }
        }
    }
}

// ---- epilogue: out[b] = dot(emb_dise[b], emb_user[b]) ----
__global__ __launch_bounds__(256) void k_dot(const float* __restrict__ ed,
                                             const float* __restrict__ eu,
                                             float* __restrict__ out) {
    const int lane = threadIdx.x & 63;
    const int b = rfl((int)((blockIdx.x * blockDim.x + threadIdx.x) >> 6));
    float pr = ed[(size_t)b * 64 + lane] * eu[(size_t)b * 64 + lane];
#pragma unroll
    for (int off = 32; off > 0; off >>= 1) pr += __shfl_down(pr, off, 64);
    if (lane == 0) out[b] = pr;
}

extern "C" void kernel_launch(void* const* d_in, const int* in_sizes, int n_in,
                              void* d_out, int out_size, void* d_ws, size_t ws_size,
                              hipStream_t stream) {
    const float* E_s  = (const float*)d_in[0];
    const float* E_d  = (const float*)d_in[1];
    const float* W_dsd_21 = (const float*)d_in[2];
    const float* W_dsd_22 = (const float*)d_in[3];
    const float* W_dsd_11 = (const float*)d_in[4];
    const float* W_dsd_12 = (const float*)d_in[5];
    const float* W_usu_3  = (const float*)d_in[6];
    const float* W_usu_21 = (const float*)d_in[7];
    const float* W_usu_22 = (const float*)d_in[8];
    const float* W_usu_1  = (const float*)d_in[9];
    const int* label = (const int*)d_in[10];
    const int* dsd_1 = (const int*)d_in[11];
    const int* dsd_2 = (const int*)d_in[12];
    const int* usu_1 = (const int*)d_in[13];
    const int* usu_2 = (const int*)d_in[14];
    const int* usu_3 = (const int*)d_in[15];
    float* out = (float*)d_out;

    // ws: Ebf [50001*64 bf16 = 6,400,128 B] | emb_dise [256 KB] | emb_user [256 KB]
    unsigned short* Ebf = (unsigned short*)d_ws;
    float* emb_dise = (float*)((char*)d_ws + 6400128);
    float* emb_user = emb_dise + 1024 * 64;

    k_cvt<<<1563, 256, 0, stream>>>(E_s, Ebf);
    k_main<<<1280, 512, 0, stream>>>(E_s, Ebf, E_d,
                                     W_dsd_21, W_dsd_22, W_dsd_11, W_dsd_12,
                                     W_usu_3, W_usu_21, W_usu_22, W_usu_1,
                                     label, dsd_1, dsd_2, usu_1, usu_2, usu_3,
                                     emb_dise, emb_user);
    k_dot<<<256, 256, 0, stream>>>(emb_dise, emb_user, out);
}